// Round 10
// baseline (570.492 us; speedup 1.0000x reference)
//
#include <hip/hip_runtime.h>
#include <math.h>

typedef __attribute__((ext_vector_type(8))) short short8;   // 8 bf16 = 4 VGPR
typedef __attribute__((ext_vector_type(4))) float f32x4;

__device__ inline unsigned short f2bf(float f) {
    unsigned int u = __float_as_uint(f);
    u += 0x7fffu + ((u >> 16) & 1u);          // RNE
    return (unsigned short)(u >> 16);
}
__device__ inline float bf2f(unsigned int h) { return __uint_as_float(h << 16); }
__device__ inline unsigned pack2(float a, float b) {
    return (unsigned)f2bf(a) | ((unsigned)f2bf(b) << 16);
}

#define GLOAD_LDS16(gp, lp)                                                              \
    __builtin_amdgcn_global_load_lds(                                                    \
        (const __attribute__((address_space(1))) unsigned int*)(const void*)(gp),        \
        (__attribute__((address_space(3))) unsigned int*)(void*)(lp), 16, 0, 0)

// ---------------- fused prep: deg/cnt init + x->bf16 + prev_h->bf16 ----------------

__global__ void prep_k(const float* __restrict__ x, const float* __restrict__ ph,
                       float* __restrict__ deg, int* __restrict__ cnt,
                       unsigned short* __restrict__ zx, unsigned short* __restrict__ phb, int N) {
    int t = blockIdx.x * blockDim.x + threadIdx.x;
    if (t < N) { deg[t] = 1.0f; cnt[t] = 0; return; }
    t -= N;
    if (t < N * 32) {           // cvt_x -> zx cols 128..255
        int r = t >> 5, c4 = (t & 31) * 4;
        float4 v = *(const float4*)&x[(size_t)r * 128 + c4];
        uint2 o; o.x = pack2(v.x, v.y); o.y = pack2(v.z, v.w);
        *(uint2*)&zx[(size_t)r * 256 + 128 + c4] = o;
        return;
    }
    t -= N * 32;
    if (t < N * 64) {           // cvt_ph
        int r = t >> 6, c4 = (t & 63) * 4;
        float4 v = *(const float4*)&ph[(size_t)r * 256 + c4];
        uint2 o; o.x = pack2(v.x, v.y); o.y = pack2(v.z, v.w);
        *(uint2*)&phb[(size_t)r * 256 + c4] = o;
    }
}

// ---------------- weights -> bf16 transposed + fused biases ----------------
// thread space: 32768 (W1) + 32768 (W2) + 6*65536 + 768 (biases) = 459520

__global__ void cvtwb_k(const float* W1, const float* W2,
                        const float* Wxz, const float* Whz, const float* Wxr, const float* Whr,
                        const float* Wxh, const float* Whh,
                        const float* bxz, const float* bhz, const float* bxr, const float* bhr,
                        const float* bxh, const float* bhh,
                        unsigned short* Bt1, unsigned short* Bt2,
                        unsigned short* BtZR, unsigned short* BtH,
                        float* bZR, float* bH) {
    int t = blockIdx.x * blockDim.x + threadIdx.x;
    if (t < 32768) { int k = t >> 8, n = t & 255; Bt1[(size_t)n * 128 + k] = f2bf(W1[t]); return; }
    t -= 32768;
    if (t < 32768) { int k = t >> 7, n = t & 127; Bt2[(size_t)n * 256 + k] = f2bf(W2[t]); return; }
    t -= 32768;
    if (t < 65536) { int k = t >> 8, n = t & 255; BtZR[(size_t)n * 512 + k] = f2bf(Wxz[t]); return; }
    t -= 65536;
    if (t < 65536) { int k = t >> 8, n = t & 255; BtZR[(size_t)n * 512 + 256 + k] = f2bf(Whz[t]); return; }
    t -= 65536;
    if (t < 65536) { int k = t >> 8, n = t & 255; BtZR[(size_t)(256 + n) * 512 + k] = f2bf(Wxr[t]); return; }
    t -= 65536;
    if (t < 65536) { int k = t >> 8, n = t & 255; BtZR[(size_t)(256 + n) * 512 + 256 + k] = f2bf(Whr[t]); return; }
    t -= 65536;
    if (t < 65536) { int k = t >> 8, n = t & 255; BtH[(size_t)n * 512 + k] = f2bf(Wxh[t]); return; }
    t -= 65536;
    if (t < 65536) { int k = t >> 8, n = t & 255; BtH[(size_t)n * 512 + 256 + k] = f2bf(Whh[t]); return; }
    t -= 65536;
    if (t < 256)       bZR[t] = bxz[t] + bhz[t];
    else if (t < 512)  bZR[t] = bxr[t - 256] + bhr[t - 256];
    else if (t < 768)  bH[t - 512] = bxh[t - 512] + bhh[t - 512];
}

// ---------------- degree / CSR ----------------

__global__ void deg_cnt_k(const int* __restrict__ dst, const float* __restrict__ w,
                          float* deg, int* cnt, int E) {
    int e = blockIdx.x * blockDim.x + threadIdx.x;
    if (e < E) { int d = dst[e]; atomicAdd(&deg[d], w[e]); atomicAdd(&cnt[d], 1); }
}

__global__ void dinv_k(float* deg, int N) {
    int i = blockIdx.x * blockDim.x + threadIdx.x;
    if (i < N) { float d = deg[i]; deg[i] = d > 0.f ? rsqrtf(d) : 0.f; }
}

// hierarchical exclusive scan of cnt[0..N) -> rp[0..N], cnt becomes fill cursor
__global__ void scan1_k(const int* __restrict__ cnt, int* __restrict__ bsum, int N) {
    __shared__ int ws_[4];
    int b = blockIdx.x, t = threadIdx.x;
    int i = b * 256 + t;
    int v = (i < N) ? cnt[i] : 0;
    int lane = t & 63, wv = t >> 6;
    #pragma unroll
    for (int o = 1; o < 64; o <<= 1) { int u = __shfl_up(v, o, 64); if (lane >= o) v += u; }
    if (lane == 63) ws_[wv] = v;
    __syncthreads();
    if (t == 0) bsum[b] = ws_[0] + ws_[1] + ws_[2] + ws_[3];
}

__global__ void scan2_k(int* __restrict__ bsum, int nb) {
    __shared__ int ws_[4];
    int t = threadIdx.x;
    int v = (t < nb) ? bsum[t] : 0;
    int orig = v;
    int lane = t & 63, wv = t >> 6;
    #pragma unroll
    for (int o = 1; o < 64; o <<= 1) { int u = __shfl_up(v, o, 64); if (lane >= o) v += u; }
    if (lane == 63) ws_[wv] = v;
    __syncthreads();
    int add = 0;
    for (int k = 0; k < wv; ++k) add += ws_[k];
    if (t < nb) bsum[t] = v + add - orig;     // exclusive block offset
}

__global__ void scan3_k(int* __restrict__ cnt, const int* __restrict__ bsum,
                        int* __restrict__ rp, int N) {
    __shared__ int ws_[4];
    int b = blockIdx.x, t = threadIdx.x;
    int i = b * 256 + t;
    int v = (i < N) ? cnt[i] : 0;
    int orig = v;
    int lane = t & 63, wv = t >> 6;
    #pragma unroll
    for (int o = 1; o < 64; o <<= 1) { int u = __shfl_up(v, o, 64); if (lane >= o) v += u; }
    if (lane == 63) ws_[wv] = v;
    __syncthreads();
    int add = bsum[b];
    for (int k = 0; k < wv; ++k) add += ws_[k];
    int incl = v + add;
    if (i < N) {
        rp[i + 1] = incl;
        cnt[i] = incl - orig;                 // exclusive -> fill cursor
        if (i == 0) rp[0] = 0;
    }
}

__global__ void fill_csr_k(const int* __restrict__ src, const int* __restrict__ dst,
                           const float* __restrict__ w, const float* __restrict__ dinv,
                           int* ofs, int* __restrict__ csr_src, float* __restrict__ csr_norm, int E) {
    int e = blockIdx.x * blockDim.x + threadIdx.x;
    if (e < E) {
        int s = src[e], d = dst[e];
        int p = atomicAdd(&ofs[d], 1);
        csr_src[p] = s;
        csr_norm[p] = dinv[s] * w[e] * dinv[d];
    }
}

// ---------------- CSR gather (bf16 in, f32 accum, bf16 out) ----------------
template <int EPI>
__global__ void agg_bf_k(const int* __restrict__ rp, const int* __restrict__ cs,
                         const float* __restrict__ cn,
                         const unsigned short* __restrict__ X, int ldx2, int xo2,
                         const float* __restrict__ dinv, const float* __restrict__ bias,
                         unsigned short* __restrict__ Y, int ldy2, int yo2, int N) {
    int wid = (blockIdx.x * blockDim.x + threadIdx.x) >> 6;
    int lane = threadIdx.x & 63;
    if (wid >= N) return;
    const unsigned int* Xu = (const unsigned int*)X;
    float dv = dinv[wid]; dv *= dv;
    unsigned int sv = Xu[(size_t)wid * ldx2 + xo2 + lane];
    float ax = bf2f(sv & 0xffffu) * dv, ay = bf2f(sv >> 16) * dv;
    int p = rp[wid], pe = rp[wid + 1];
    for (; p + 4 <= pe; p += 4) {
        int s0 = cs[p], s1 = cs[p+1], s2 = cs[p+2], s3 = cs[p+3];
        float n0 = cn[p], n1 = cn[p+1], n2 = cn[p+2], n3 = cn[p+3];
        unsigned int v0 = Xu[(size_t)s0 * ldx2 + xo2 + lane];
        unsigned int v1 = Xu[(size_t)s1 * ldx2 + xo2 + lane];
        unsigned int v2 = Xu[(size_t)s2 * ldx2 + xo2 + lane];
        unsigned int v3 = Xu[(size_t)s3 * ldx2 + xo2 + lane];
        ax = fmaf(bf2f(v0 & 0xffffu), n0, ax); ay = fmaf(bf2f(v0 >> 16), n0, ay);
        ax = fmaf(bf2f(v1 & 0xffffu), n1, ax); ay = fmaf(bf2f(v1 >> 16), n1, ay);
        ax = fmaf(bf2f(v2 & 0xffffu), n2, ax); ay = fmaf(bf2f(v2 >> 16), n2, ay);
        ax = fmaf(bf2f(v3 & 0xffffu), n3, ax); ay = fmaf(bf2f(v3 >> 16), n3, ay);
    }
    for (; p < pe; ++p) {
        int s = cs[p]; float nv = cn[p];
        unsigned int v = Xu[(size_t)s * ldx2 + xo2 + lane];
        ax = fmaf(bf2f(v & 0xffffu), nv, ax); ay = fmaf(bf2f(v >> 16), nv, ay);
    }
    if (EPI == 1) {
        ax = fmaxf(ax + bias[lane * 2], 0.f);
        ay = fmaxf(ay + bias[lane * 2 + 1], 0.f);
    }
    ((unsigned int*)Y)[(size_t)wid * ldy2 + yo2 + lane] = pack2(ax, ay);
}

// ---------------- head ----------------

__global__ void colsum_bf_k(const unsigned short* __restrict__ Z, float* zsum, int N) {
    int c = threadIdx.x;
    int rpb = (N + gridDim.x - 1) / gridDim.x;
    int r0 = blockIdx.x * rpb, r1 = min(N, r0 + rpb);
    float s = 0.f;
    for (int r = r0; r < r1; ++r) s += bf2f((unsigned int)Z[(size_t)r * 256 + c]);
    atomicAdd(&zsum[c], s);
}

__global__ void head_k(const float* __restrict__ zsum, const float* __restrict__ Wh,
                       const float* __restrict__ bh, float* __restrict__ out, float invN) {
    __shared__ float red[128];
    int c = threadIdx.x;
    red[c] = zsum[c] * invN * Wh[c];
    __syncthreads();
    for (int s = 64; s > 0; s >>= 1) {
        if (c < s) red[c] += red[c + s];
        __syncthreads();
    }
    if (c == 0) out[0] = red[0] + bh[0];
}

// ---------------- bf16 MFMA GEMM, 128x128 tile, 512 threads (8 waves) ----------------
// A through LDS (double-buffered, swizzled, global_load_lds);
// B (weights, L2-resident) direct from global into registers, double-buffered
// in named sets b0/b1 with a 2-step unrolled K-loop; counted vmcnt(5).
// Transposed-acc epilogue (mfma(b, a)): row = ...+m15, 4 consecutive cols per lane.

enum { EPI_G = 0, EPI_P = 1, EPI_ZR = 2, EPI_H = 3 };

__global__ __launch_bounds__(512, 4)
void mm_bf16_k(const unsigned short* __restrict__ A0, const unsigned short* __restrict__ A1,
               int lda0, int lda1, int kb,
               const unsigned short* __restrict__ Bt, int K, int M, int ncb,
               const float* __restrict__ bias,
               const unsigned short* __restrict__ xb1, const unsigned short* __restrict__ xb2,
               void* __restrict__ out, void* __restrict__ out2, int epi)
{
    __shared__ unsigned short Als[2][4096];

    // XCD-bijective swizzle, bcol fast
    int nwg = gridDim.x;
    int bid = blockIdx.x;
    int q = nwg >> 3, r = nwg & 7;
    int xcd = bid & 7;
    int wg = (xcd < r ? xcd * (q + 1) : r * (q + 1) + (xcd - r) * q) + (bid >> 3);
    int brow = wg / ncb, bcol = wg - brow * ncb;
    int row0 = brow * 128, col0 = bcol * 128;

    int t = threadIdx.x;
    int w = t >> 6, lane = t & 63;
    int wr = w >> 1, wc = w & 1;
    int m15 = lane & 15, g = lane >> 4;

    // A staging: thread t covers row t>>2 (0..127), swizzled k-slot
    int srow = t >> 2;
    int skk  = (((t & 3) ^ ((t >> 3) & 3)) << 3);

    f32x4 acc[2][4];
    #pragma unroll
    for (int i = 0; i < 2; ++i)
        #pragma unroll
        for (int j = 0; j < 4; ++j)
            #pragma unroll
            for (int qq = 0; qq < 4; ++qq) acc[i][j][qq] = 0.f;

    auto stageA = [&](int buf, int kt) {
        const unsigned short* Ap = A0; int lda = lda0; int ka = kt;
        if (kt >= kb) { Ap = A1; lda = lda1; ka = kt - kb; }
        int gr = row0 + srow; gr = gr < M ? gr : M - 1;
        GLOAD_LDS16(&Ap[(size_t)gr * lda + ka + skk], &Als[buf][w * 512]);
    };

    // B fragment base for this lane: row = col0 + wc*64 + ns*16 + m15, k offset g*8
    const unsigned short* Bbase = &Bt[(size_t)(col0 + wc * 64 + m15) * K + g * 8];

    short8 b0[4], b1[4];
    #define LOADB(dst, kt)                                                        \
        { _Pragma("unroll")                                                       \
          for (int ns = 0; ns < 4; ++ns)                                          \
              dst[ns] = *(const short8*)&Bbase[(size_t)(ns * 16) * K + (kt)]; }

    int NT = K >> 5;            // always even (K in {128,256,512})
    stageA(0, 0);
    LOADB(b0, 0);

    for (int ti = 0; ti < NT; ti += 2) {
        // ---- even step: LDS buf 0, regs b0; prefetch ti+1 -> buf1, b1 ----
        stageA(1, (ti + 1) << 5);
        LOADB(b1, (ti + 1) << 5);
        asm volatile("s_waitcnt vmcnt(5)" ::: "memory");   // A(ti)+b0 complete
        __builtin_amdgcn_s_barrier();
        __builtin_amdgcn_sched_barrier(0);
        short8 af0[2];
        #pragma unroll
        for (int ms = 0; ms < 2; ++ms) {
            int rt = wr * 32 + ms * 16 + m15;
            af0[ms] = *(const short8*)&Als[0][rt * 32 + ((g ^ ((rt >> 1) & 3)) << 3)];
        }
        asm volatile("s_waitcnt lgkmcnt(0)" ::: "memory");
        __builtin_amdgcn_sched_barrier(0);
        __builtin_amdgcn_s_barrier();                      // buf0 reads done
        #pragma unroll
        for (int ms = 0; ms < 2; ++ms)
            #pragma unroll
            for (int ns = 0; ns < 4; ++ns)
                acc[ms][ns] = __builtin_amdgcn_mfma_f32_16x16x32_bf16(b0[ns], af0[ms], acc[ms][ns], 0, 0, 0);

        // ---- odd step: LDS buf 1, regs b1; prefetch ti+2 -> buf0, b0 ----
        if (ti + 2 < NT) {
            stageA(0, (ti + 2) << 5);
            LOADB(b0, (ti + 2) << 5);
            asm volatile("s_waitcnt vmcnt(5)" ::: "memory");  // A(ti+1)+b1 complete
        } else {
            asm volatile("s_waitcnt vmcnt(0)" ::: "memory");
        }
        __builtin_amdgcn_s_barrier();
        __builtin_amdgcn_sched_barrier(0);
        short8 af1[2];
        #pragma unroll
        for (int ms = 0; ms < 2; ++ms) {
            int rt = wr * 32 + ms * 16 + m15;
            af1[ms] = *(const short8*)&Als[1][rt * 32 + ((g ^ ((rt >> 1) & 3)) << 3)];
        }
        asm volatile("s_waitcnt lgkmcnt(0)" ::: "memory");
        __builtin_amdgcn_sched_barrier(0);
        __builtin_amdgcn_s_barrier();                      // buf1 reads done
        #pragma unroll
        for (int ms = 0; ms < 2; ++ms)
            #pragma unroll
            for (int ns = 0; ns < 4; ++ns)
                acc[ms][ns] = __builtin_amdgcn_mfma_f32_16x16x32_bf16(b1[ns], af1[ms], acc[ms][ns], 0, 0, 0);
    }
    #undef LOADB

    // epilogue: row = row0 + wr*32 + ms*16 + m15 ; cols = col0 + wc*64 + ns*16 + g*4 + (0..3)
    #pragma unroll
    for (int ms = 0; ms < 2; ++ms) {
        int row = row0 + wr * 32 + ms * 16 + m15;
        bool rok = row < M;
        #pragma unroll
        for (int ns = 0; ns < 4; ++ns) {
            int col = col0 + wc * 64 + ns * 16 + g * 4;
            f32x4 a = acc[ms][ns];
            if (epi == EPI_G) {
                float4 bv = *(const float4*)&bias[col];
                uint2 p4 = *(const uint2*)&xb1[(size_t)row * 256 + col];
                uint2 o;
                o.x = pack2(fmaxf(a[0] + bv.x, 0.f) + bf2f(p4.x & 0xffffu),
                            fmaxf(a[1] + bv.y, 0.f) + bf2f(p4.x >> 16));
                o.y = pack2(fmaxf(a[2] + bv.z, 0.f) + bf2f(p4.y & 0xffffu),
                            fmaxf(a[3] + bv.w, 0.f) + bf2f(p4.y >> 16));
                if (rok) *(uint2*)&((unsigned short*)out)[(size_t)row * 256 + col] = o;
            } else if (epi == EPI_P) {
                uint2 o;
                o.x = pack2(a[0], a[1]);
                o.y = pack2(a[2], a[3]);
                if (rok) *(uint2*)&((unsigned short*)out)[(size_t)row * 128 + col] = o;
            } else if (epi == EPI_ZR) {
                float4 bv = *(const float4*)&bias[col];
                float s0 = 1.f / (1.f + __expf(-(a[0] + bv.x)));
                float s1 = 1.f / (1.f + __expf(-(a[1] + bv.y)));
                float s2 = 1.f / (1.f + __expf(-(a[2] + bv.z)));
                float s3 = 1.f / (1.f + __expf(-(a[3] + bv.w)));
                if (col < 256) {
                    uint2 o; o.x = pack2(s0, s1); o.y = pack2(s2, s3);
                    if (rok) *(uint2*)&((unsigned short*)out)[(size_t)row * 256 + col] = o;
                } else {
                    int c2 = col - 256;
                    uint2 p4 = *(const uint2*)&xb1[(size_t)row * 256 + c2];
                    uint2 o;
                    o.x = pack2(bf2f(p4.x & 0xffffu) * s0, bf2f(p4.x >> 16) * s1);
                    o.y = pack2(bf2f(p4.y & 0xffffu) * s2, bf2f(p4.y >> 16) * s3);
                    if (rok) *(uint2*)&((unsigned short*)out2)[(size_t)row * 256 + c2] = o;
                }
            } else {  // EPI_H
                float4 bv = *(const float4*)&bias[col];
                uint2 z4 = *(const uint2*)&xb2[(size_t)row * 256 + col];
                uint2 p4 = *(const uint2*)&xb1[(size_t)row * 256 + col];
                float4 o;
                {
                    float s = a[0] + bv.x, e = __expf(2.f * s);
                    float ht = 1.f - 2.f / (e + 1.f);
                    float Zt = bf2f(z4.x & 0xffffu), ph = bf2f(p4.x & 0xffffu);
                    o.x = Zt * ph + (1.f - Zt) * ht;
                }
                {
                    float s = a[1] + bv.y, e = __expf(2.f * s);
                    float ht = 1.f - 2.f / (e + 1.f);
                    float Zt = bf2f(z4.x >> 16), ph = bf2f(p4.x >> 16);
                    o.y = Zt * ph + (1.f - Zt) * ht;
                }
                {
                    float s = a[2] + bv.z, e = __expf(2.f * s);
                    float ht = 1.f - 2.f / (e + 1.f);
                    float Zt = bf2f(z4.y & 0xffffu), ph = bf2f(p4.y & 0xffffu);
                    o.z = Zt * ph + (1.f - Zt) * ht;
                }
                {
                    float s = a[3] + bv.w, e = __expf(2.f * s);
                    float ht = 1.f - 2.f / (e + 1.f);
                    float Zt = bf2f(z4.y >> 16), ph = bf2f(p4.y >> 16);
                    o.w = Zt * ph + (1.f - Zt) * ht;
                }
                if (rok) *(float4*)&((float*)out)[(size_t)row * 256 + col] = o;
            }
        }
    }
}

// ---------------- launch ----------------

extern "C" void kernel_launch(void* const* d_in, const int* in_sizes, int n_in,
                              void* d_out, int out_size, void* d_ws, size_t ws_size,
                              hipStream_t stream) {
    const float* x      = (const float*)d_in[0];
    const int*   ei     = (const int*)d_in[1];
    const float* ew     = (const float*)d_in[2];
    const float* prev_h = (const float*)d_in[3];
    const float* W1  = (const float*)d_in[4];  const float* b1  = (const float*)d_in[5];
    const float* W2  = (const float*)d_in[6];  const float* b2  = (const float*)d_in[7];
    const float* Wxz = (const float*)d_in[8];  const float* bxz = (const float*)d_in[9];
    const float* Whz = (const float*)d_in[10]; const float* bhz = (const float*)d_in[11];
    const float* Wxr = (const float*)d_in[12]; const float* bxr = (const float*)d_in[13];
    const float* Whr = (const float*)d_in[14]; const float* bhr = (const float*)d_in[15];
    const float* Wxh = (const float*)d_in[16]; const float* bxh = (const float*)d_in[17];
    const float* Whh = (const float*)d_in[18]; const float* bhh = (const float*)d_in[19];
    const float* Whead = (const float*)d_in[20]; const float* bhead = (const float*)d_in[21];

    const int N = in_sizes[0] / 128;
    const int E = in_sizes[2];
    const int* esrc = ei;
    const int* edst = ei + E;

    float* ws = (float*)d_ws;
    size_t o = 0;
    float* dinv     = ws + o; o += (size_t)N;
    int*   cnt      = (int*)(ws + o); o += (size_t)N;
    int*   rowp     = (int*)(ws + o); o += (size_t)N + 4;
    int*   bsum     = (int*)(ws + o); o += 256;
    int*   csr_src  = (int*)(ws + o); o += (size_t)E;
    float* csr_norm = ws + o; o += (size_t)E;
    unsigned short* zx   = (unsigned short*)(ws + o); o += (size_t)N * 128;  // [N,256]: z | x
    unsigned short* phb  = (unsigned short*)(ws + o); o += (size_t)N * 128;  // prev_h bf16
    unsigned short* buf1 = (unsigned short*)(ws + o); o += (size_t)N * 128;  // t -> gw2 -> q
    unsigned short* Zbf  = (unsigned short*)(ws + o); o += (size_t)N * 128;  // g_bf -> Z bf16
    unsigned short* Bt1  = (unsigned short*)(ws + o); o += 16384;
    unsigned short* Bt2  = (unsigned short*)(ws + o); o += 16384;
    unsigned short* BtZR = (unsigned short*)(ws + o); o += 131072;
    unsigned short* BtH  = (unsigned short*)(ws + o); o += 65536;
    float* bZR      = ws + o; o += 512;
    float* bH       = ws + o; o += 256;
    float* zsum     = ws + o; o += 128;

    unsigned short* g_bf = Zbf;
    float* hout = (float*)d_out + 1;

    const int TPB = 256;
    int gE = (E + TPB - 1) / TPB;
    int gAgg = (N * 64 + TPB - 1) / TPB;
    int nb = (N + 127) / 128;
    int nsb = (N + 255) / 256;          // scan blocks (must be <= 256)

    // prep: deg/cnt init + x,prev_h -> bf16
    {
        long long tot = (long long)N * 97;
        prep_k<<<(int)((tot + TPB - 1) / TPB), TPB, 0, stream>>>(x, prev_h, dinv, cnt, zx, phb, N);
    }
    // weights + biases: 2*32768 + 6*65536 + 768 = 459520 threads
    {
        const int cvtw_total = 2 * 32768 + 6 * 65536 + 768;
        cvtwb_k<<<(cvtw_total + TPB - 1) / TPB, TPB, 0, stream>>>(
            W1, W2, Wxz, Whz, Wxr, Whr, Wxh, Whh,
            bxz, bhz, bxr, bhr, bxh, bhh, Bt1, Bt2, BtZR, BtH, bZR, bH);
    }

    // degree + CSR
    deg_cnt_k<<<gE, TPB, 0, stream>>>(edst, ew, dinv, cnt, E);
    dinv_k<<<(N + TPB - 1) / TPB, TPB, 0, stream>>>(dinv, N);
    scan1_k<<<nsb, 256, 0, stream>>>(cnt, bsum, N);
    scan2_k<<<1, 256, 0, stream>>>(bsum, nsb);
    scan3_k<<<nsb, 256, 0, stream>>>(cnt, bsum, rowp, N);
    fill_csr_k<<<gE, TPB, 0, stream>>>(esrc, edst, ew, dinv, cnt, csr_src, csr_norm, E);

    // t = agg(x)
    agg_bf_k<0><<<gAgg, TPB, 0, stream>>>(rowp, csr_src, csr_norm, zx, 128, 64, dinv,
                                          nullptr, buf1, 64, 0, N);

    // g = relu(t@W1 + b1) + prev_h
    mm_bf16_k<<<nb * 2, 512, 0, stream>>>(buf1, buf1, 128, 128, 128, Bt1, 128, N, 2,
                                          b1, phb, nullptr, g_bf, nullptr, EPI_G);
    // gw2 = g@W2
    mm_bf16_k<<<nb, 512, 0, stream>>>(g_bf, g_bf, 256, 256, 256, Bt2, 256, N, 1,
                                      nullptr, nullptr, nullptr, buf1, nullptr, EPI_P);
    // z = relu(agg(gw2) + b2)
    agg_bf_k<1><<<gAgg, TPB, 0, stream>>>(rowp, csr_src, csr_norm, buf1, 64, 0, dinv,
                                          b2, zx, 128, 0, N);

    // head
    hipMemsetAsync(zsum, 0, 128 * sizeof(float), stream);
    colsum_bf_k<<<512, 128, 0, stream>>>(zx, zsum, N);
    head_k<<<1, 128, 0, stream>>>(zsum, Whead, bhead, (float*)d_out, 1.0f / (float)N);

    // Z|R fused GEMM
    mm_bf16_k<<<nb * 4, 512, 0, stream>>>(zx, phb, 256, 256, 256, BtZR, 512, N, 4,
                                          bZR, phb, nullptr, Zbf, buf1, EPI_ZR);
    // h GEMM
    mm_bf16_k<<<nb * 2, 512, 0, stream>>>(zx, buf1, 256, 256, 256, BtH, 512, N, 2,
                                          bH, phb, Zbf, hout, nullptr, EPI_H);
}

// Round 11
// 466.477 us; speedup vs baseline: 1.2230x; 1.2230x over previous
//
#include <hip/hip_runtime.h>
#include <math.h>

typedef __attribute__((ext_vector_type(8))) short short8;   // 8 bf16 = 4 VGPR
typedef __attribute__((ext_vector_type(4))) float f32x4;

__device__ inline unsigned short f2bf(float f) {
    unsigned int u = __float_as_uint(f);
    u += 0x7fffu + ((u >> 16) & 1u);          // RNE
    return (unsigned short)(u >> 16);
}
__device__ inline float bf2f(unsigned int h) { return __uint_as_float(h << 16); }
__device__ inline unsigned pack2(float a, float b) {
    return (unsigned)f2bf(a) | ((unsigned)f2bf(b) << 16);
}

#define GLOAD_LDS16(gp, lp)                                                              \
    __builtin_amdgcn_global_load_lds(                                                    \
        (const __attribute__((address_space(1))) unsigned int*)(const void*)(gp),        \
        (__attribute__((address_space(3))) unsigned int*)(void*)(lp), 16, 0, 0)

// ---------------- fused prep: deg/cnt init + x->bf16 + prev_h->bf16 ----------------

__global__ void prep_k(const float* __restrict__ x, const float* __restrict__ ph,
                       float* __restrict__ deg, int* __restrict__ cnt,
                       unsigned short* __restrict__ zx, unsigned short* __restrict__ phb, int N) {
    int t = blockIdx.x * blockDim.x + threadIdx.x;
    if (t < N) { deg[t] = 1.0f; cnt[t] = 0; return; }
    t -= N;
    if (t < N * 32) {           // cvt_x -> zx cols 128..255
        int r = t >> 5, c4 = (t & 31) * 4;
        float4 v = *(const float4*)&x[(size_t)r * 128 + c4];
        uint2 o; o.x = pack2(v.x, v.y); o.y = pack2(v.z, v.w);
        *(uint2*)&zx[(size_t)r * 256 + 128 + c4] = o;
        return;
    }
    t -= N * 32;
    if (t < N * 64) {           // cvt_ph
        int r = t >> 6, c4 = (t & 63) * 4;
        float4 v = *(const float4*)&ph[(size_t)r * 256 + c4];
        uint2 o; o.x = pack2(v.x, v.y); o.y = pack2(v.z, v.w);
        *(uint2*)&phb[(size_t)r * 256 + c4] = o;
    }
}

// ---------------- weights -> bf16 transposed + fused biases ----------------
// thread space: 32768 (W1) + 32768 (W2) + 6*65536 + 768 (biases) = 459520

__global__ void cvtwb_k(const float* W1, const float* W2,
                        const float* Wxz, const float* Whz, const float* Wxr, const float* Whr,
                        const float* Wxh, const float* Whh,
                        const float* bxz, const float* bhz, const float* bxr, const float* bhr,
                        const float* bxh, const float* bhh,
                        unsigned short* Bt1, unsigned short* Bt2,
                        unsigned short* BtZR, unsigned short* BtH,
                        float* bZR, float* bH) {
    int t = blockIdx.x * blockDim.x + threadIdx.x;
    if (t < 32768) { int k = t >> 8, n = t & 255; Bt1[(size_t)n * 128 + k] = f2bf(W1[t]); return; }
    t -= 32768;
    if (t < 32768) { int k = t >> 7, n = t & 127; Bt2[(size_t)n * 256 + k] = f2bf(W2[t]); return; }
    t -= 32768;
    if (t < 65536) { int k = t >> 8, n = t & 255; BtZR[(size_t)n * 512 + k] = f2bf(Wxz[t]); return; }
    t -= 65536;
    if (t < 65536) { int k = t >> 8, n = t & 255; BtZR[(size_t)n * 512 + 256 + k] = f2bf(Whz[t]); return; }
    t -= 65536;
    if (t < 65536) { int k = t >> 8, n = t & 255; BtZR[(size_t)(256 + n) * 512 + k] = f2bf(Wxr[t]); return; }
    t -= 65536;
    if (t < 65536) { int k = t >> 8, n = t & 255; BtZR[(size_t)(256 + n) * 512 + 256 + k] = f2bf(Whr[t]); return; }
    t -= 65536;
    if (t < 65536) { int k = t >> 8, n = t & 255; BtH[(size_t)n * 512 + k] = f2bf(Wxh[t]); return; }
    t -= 65536;
    if (t < 65536) { int k = t >> 8, n = t & 255; BtH[(size_t)n * 512 + 256 + k] = f2bf(Whh[t]); return; }
    t -= 65536;
    if (t < 256)       bZR[t] = bxz[t] + bhz[t];
    else if (t < 512)  bZR[t] = bxr[t - 256] + bhr[t - 256];
    else if (t < 768)  bH[t - 512] = bxh[t - 512] + bhh[t - 512];
}

// ---------------- degree / CSR ----------------

__global__ void deg_cnt_k(const int* __restrict__ dst, const float* __restrict__ w,
                          float* deg, int* cnt, int E) {
    int e = blockIdx.x * blockDim.x + threadIdx.x;
    if (e < E) { int d = dst[e]; atomicAdd(&deg[d], w[e]); atomicAdd(&cnt[d], 1); }
}

__global__ void dinv_k(float* deg, int N) {
    int i = blockIdx.x * blockDim.x + threadIdx.x;
    if (i < N) { float d = deg[i]; deg[i] = d > 0.f ? rsqrtf(d) : 0.f; }
}

// hierarchical exclusive scan of cnt[0..N) -> rp[0..N], cnt becomes fill cursor
__global__ void scan1_k(const int* __restrict__ cnt, int* __restrict__ bsum, int N) {
    __shared__ int ws_[4];
    int b = blockIdx.x, t = threadIdx.x;
    int i = b * 256 + t;
    int v = (i < N) ? cnt[i] : 0;
    int lane = t & 63, wv = t >> 6;
    #pragma unroll
    for (int o = 1; o < 64; o <<= 1) { int u = __shfl_up(v, o, 64); if (lane >= o) v += u; }
    if (lane == 63) ws_[wv] = v;
    __syncthreads();
    if (t == 0) bsum[b] = ws_[0] + ws_[1] + ws_[2] + ws_[3];
}

__global__ void scan2_k(int* __restrict__ bsum, int nb) {
    __shared__ int ws_[4];
    int t = threadIdx.x;
    int v = (t < nb) ? bsum[t] : 0;
    int orig = v;
    int lane = t & 63, wv = t >> 6;
    #pragma unroll
    for (int o = 1; o < 64; o <<= 1) { int u = __shfl_up(v, o, 64); if (lane >= o) v += u; }
    if (lane == 63) ws_[wv] = v;
    __syncthreads();
    int add = 0;
    for (int k = 0; k < wv; ++k) add += ws_[k];
    if (t < nb) bsum[t] = v + add - orig;     // exclusive block offset
}

__global__ void scan3_k(int* __restrict__ cnt, const int* __restrict__ bsum,
                        int* __restrict__ rp, int N) {
    __shared__ int ws_[4];
    int b = blockIdx.x, t = threadIdx.x;
    int i = b * 256 + t;
    int v = (i < N) ? cnt[i] : 0;
    int orig = v;
    int lane = t & 63, wv = t >> 6;
    #pragma unroll
    for (int o = 1; o < 64; o <<= 1) { int u = __shfl_up(v, o, 64); if (lane >= o) v += u; }
    if (lane == 63) ws_[wv] = v;
    __syncthreads();
    int add = bsum[b];
    for (int k = 0; k < wv; ++k) add += ws_[k];
    int incl = v + add;
    if (i < N) {
        rp[i + 1] = incl;
        cnt[i] = incl - orig;                 // exclusive -> fill cursor
        if (i == 0) rp[0] = 0;
    }
}

__global__ void fill_csr_k(const int* __restrict__ src, const int* __restrict__ dst,
                           const float* __restrict__ w, const float* __restrict__ dinv,
                           int* ofs, int* __restrict__ csr_src, float* __restrict__ csr_norm, int E) {
    int e = blockIdx.x * blockDim.x + threadIdx.x;
    if (e < E) {
        int s = src[e], d = dst[e];
        int p = atomicAdd(&ofs[d], 1);
        csr_src[p] = s;
        csr_norm[p] = dinv[s] * w[e] * dinv[d];
    }
}

// ---------------- CSR gather, 2 edges/iter (bf16 in, f32 accum, bf16 out) ----------------
// One wave per node. Half-wave h = lane>>5 handles edge p+h; lane c = lane&31
// covers cols 4c..4c+3 via uint2 (8 B). Final cross-half combine: __shfl_xor 32.
template <int EPI>
__global__ void agg_bf_k(const int* __restrict__ rp, const int* __restrict__ cs,
                         const float* __restrict__ cn,
                         const unsigned short* __restrict__ X, int ldx2, int xo2,
                         const float* __restrict__ dinv, const float* __restrict__ bias,
                         unsigned short* __restrict__ Y, int ldy2, int yo2, int N) {
    int wid = (blockIdx.x * blockDim.x + threadIdx.x) >> 6;
    int lane = threadIdx.x & 63;
    if (wid >= N) return;
    const unsigned int* Xu = (const unsigned int*)X;
    int h = lane >> 5, c = lane & 31;

    float dv = dinv[wid]; dv *= dv;
    float w0 = h ? 0.f : dv;                   // self-loop only on even half
    uint2 sv = *(const uint2*)&Xu[(size_t)wid * ldx2 + xo2 + c * 2];
    float a0 = bf2f(sv.x & 0xffffu) * w0, a1 = bf2f(sv.x >> 16) * w0;
    float a2 = bf2f(sv.y & 0xffffu) * w0, a3 = bf2f(sv.y >> 16) * w0;

    int p = rp[wid], pe = rp[wid + 1];
    for (; p + 4 <= pe; p += 4) {              // 4 edges = 2 pairs
        int sA = cs[p + h];      float nA = cn[p + h];
        int sB = cs[p + 2 + h];  float nB = cn[p + 2 + h];
        uint2 vA = *(const uint2*)&Xu[(size_t)sA * ldx2 + xo2 + c * 2];
        uint2 vB = *(const uint2*)&Xu[(size_t)sB * ldx2 + xo2 + c * 2];
        a0 = fmaf(bf2f(vA.x & 0xffffu), nA, a0); a1 = fmaf(bf2f(vA.x >> 16), nA, a1);
        a2 = fmaf(bf2f(vA.y & 0xffffu), nA, a2); a3 = fmaf(bf2f(vA.y >> 16), nA, a3);
        a0 = fmaf(bf2f(vB.x & 0xffffu), nB, a0); a1 = fmaf(bf2f(vB.x >> 16), nB, a1);
        a2 = fmaf(bf2f(vB.y & 0xffffu), nB, a2); a3 = fmaf(bf2f(vB.y >> 16), nB, a3);
    }
    if (p + 2 <= pe) {                         // one pair
        int s = cs[p + h]; float nv = cn[p + h];
        uint2 v = *(const uint2*)&Xu[(size_t)s * ldx2 + xo2 + c * 2];
        a0 = fmaf(bf2f(v.x & 0xffffu), nv, a0); a1 = fmaf(bf2f(v.x >> 16), nv, a1);
        a2 = fmaf(bf2f(v.y & 0xffffu), nv, a2); a3 = fmaf(bf2f(v.y >> 16), nv, a3);
        p += 2;
    }
    if (p < pe) {                              // odd tail: even half only
        int s = cs[p]; float nv = h ? 0.f : cn[p];
        uint2 v = *(const uint2*)&Xu[(size_t)s * ldx2 + xo2 + c * 2];
        a0 = fmaf(bf2f(v.x & 0xffffu), nv, a0); a1 = fmaf(bf2f(v.x >> 16), nv, a1);
        a2 = fmaf(bf2f(v.y & 0xffffu), nv, a2); a3 = fmaf(bf2f(v.y >> 16), nv, a3);
    }

    // combine halves
    a0 += __shfl_xor(a0, 32);
    a1 += __shfl_xor(a1, 32);
    a2 += __shfl_xor(a2, 32);
    a3 += __shfl_xor(a3, 32);

    if (EPI == 1) {
        float4 bv = *(const float4*)&bias[c * 4];
        a0 = fmaxf(a0 + bv.x, 0.f); a1 = fmaxf(a1 + bv.y, 0.f);
        a2 = fmaxf(a2 + bv.z, 0.f); a3 = fmaxf(a3 + bv.w, 0.f);
    }
    if (h == 0) {
        uint2 o; o.x = pack2(a0, a1); o.y = pack2(a2, a3);
        *(uint2*)&((unsigned int*)Y)[(size_t)wid * ldy2 + yo2 + c * 2] = o;
    }
}

// ---------------- head ----------------

__global__ void colsum_bf_k(const unsigned short* __restrict__ Z, float* zsum, int N) {
    int c = threadIdx.x;
    int rpb = (N + gridDim.x - 1) / gridDim.x;
    int r0 = blockIdx.x * rpb, r1 = min(N, r0 + rpb);
    float s = 0.f;
    for (int r = r0; r < r1; ++r) s += bf2f((unsigned int)Z[(size_t)r * 256 + c]);
    atomicAdd(&zsum[c], s);
}

__global__ void head_k(const float* __restrict__ zsum, const float* __restrict__ Wh,
                       const float* __restrict__ bh, float* __restrict__ out, float invN) {
    __shared__ float red[128];
    int c = threadIdx.x;
    red[c] = zsum[c] * invN * Wh[c];
    __syncthreads();
    for (int s = 64; s > 0; s >>= 1) {
        if (c < s) red[c] += red[c + s];
        __syncthreads();
    }
    if (c == 0) out[0] = red[0] + bh[0];
}

// ---------------- bf16 MFMA GEMM, 128x128 tile, 512 threads (8 waves) ----------------
// r9 version (REVERT of r10's B-from-global regression): A and B both via
// global_load_lds double-buffered LDS, counted vmcnt(2); transposed-acc epilogue.

enum { EPI_G = 0, EPI_P = 1, EPI_ZR = 2, EPI_H = 3 };

__global__ __launch_bounds__(512)
void mm_bf16_k(const unsigned short* __restrict__ A0, const unsigned short* __restrict__ A1,
               int lda0, int lda1, int kb,
               const unsigned short* __restrict__ Bt, int K, int M, int ncb,
               const float* __restrict__ bias,
               const unsigned short* __restrict__ xb1, const unsigned short* __restrict__ xb2,
               void* __restrict__ out, void* __restrict__ out2, int epi)
{
    __shared__ unsigned short Als[2][4096];
    __shared__ unsigned short Bls[2][4096];

    // XCD-bijective swizzle, bcol fast
    int nwg = gridDim.x;
    int bid = blockIdx.x;
    int q = nwg >> 3, r = nwg & 7;
    int xcd = bid & 7;
    int wg = (xcd < r ? xcd * (q + 1) : r * (q + 1) + (xcd - r) * q) + (bid >> 3);
    int brow = wg / ncb, bcol = wg - brow * ncb;
    int row0 = brow * 128, col0 = bcol * 128;

    int t = threadIdx.x;
    int w = t >> 6, lane = t & 63;
    int wr = w >> 1, wc = w & 1;
    int m15 = lane & 15, g = lane >> 4;

    // staging: thread t covers row t>>2 (0..127), swizzled k-slot
    int srow = t >> 2;
    int skk  = (((t & 3) ^ ((t >> 3) & 3)) << 3);

    f32x4 acc[2][4];
    #pragma unroll
    for (int i = 0; i < 2; ++i)
        #pragma unroll
        for (int j = 0; j < 4; ++j)
            #pragma unroll
            for (int qq = 0; qq < 4; ++qq) acc[i][j][qq] = 0.f;

    auto stage = [&](int buf, int kt) {
        const unsigned short* Ap = A0; int lda = lda0; int ka = kt;
        if (kt >= kb) { Ap = A1; lda = lda1; ka = kt - kb; }
        int gr = row0 + srow; gr = gr < M ? gr : M - 1;
        GLOAD_LDS16(&Ap[(size_t)gr * lda + ka + skk], &Als[buf][w * 512]);
        GLOAD_LDS16(&Bt[(size_t)(col0 + srow) * K + kt + skk], &Bls[buf][w * 512]);
    };

    int NT = K >> 5;
    stage(0, 0);
    int pb = 0;

    for (int ti = 0; ti < NT; ++ti) {
        if (ti + 1 < NT) {
            stage(pb ^ 1, (ti + 1) << 5);
            asm volatile("s_waitcnt vmcnt(2)" ::: "memory");
        } else {
            asm volatile("s_waitcnt vmcnt(0)" ::: "memory");
        }
        __builtin_amdgcn_s_barrier();
        __builtin_amdgcn_sched_barrier(0);

        short8 af[2], bfr[4];
        #pragma unroll
        for (int ms = 0; ms < 2; ++ms) {
            int rt = wr * 32 + ms * 16 + m15;
            af[ms] = *(const short8*)&Als[pb][rt * 32 + ((g ^ ((rt >> 1) & 3)) << 3)];
        }
        #pragma unroll
        for (int ns = 0; ns < 4; ++ns) {
            int nt = wc * 64 + ns * 16 + m15;
            bfr[ns] = *(const short8*)&Bls[pb][nt * 32 + ((g ^ ((nt >> 1) & 3)) << 3)];
        }
        asm volatile("s_waitcnt lgkmcnt(0)" ::: "memory");
        __builtin_amdgcn_sched_barrier(0);
        __builtin_amdgcn_s_barrier();

        #pragma unroll
        for (int ms = 0; ms < 2; ++ms)
            #pragma unroll
            for (int ns = 0; ns < 4; ++ns)
                acc[ms][ns] = __builtin_amdgcn_mfma_f32_16x16x32_bf16(bfr[ns], af[ms], acc[ms][ns], 0, 0, 0);
        pb ^= 1;
    }

    // epilogue: row = row0 + wr*32 + ms*16 + m15 ; cols = col0 + wc*64 + ns*16 + g*4 + (0..3)
    #pragma unroll
    for (int ms = 0; ms < 2; ++ms) {
        int row = row0 + wr * 32 + ms * 16 + m15;
        bool rok = row < M;
        #pragma unroll
        for (int ns = 0; ns < 4; ++ns) {
            int col = col0 + wc * 64 + ns * 16 + g * 4;
            f32x4 a = acc[ms][ns];
            if (epi == EPI_G) {
                float4 bv = *(const float4*)&bias[col];
                uint2 p4 = *(const uint2*)&xb1[(size_t)row * 256 + col];
                uint2 o;
                o.x = pack2(fmaxf(a[0] + bv.x, 0.f) + bf2f(p4.x & 0xffffu),
                            fmaxf(a[1] + bv.y, 0.f) + bf2f(p4.x >> 16));
                o.y = pack2(fmaxf(a[2] + bv.z, 0.f) + bf2f(p4.y & 0xffffu),
                            fmaxf(a[3] + bv.w, 0.f) + bf2f(p4.y >> 16));
                if (rok) *(uint2*)&((unsigned short*)out)[(size_t)row * 256 + col] = o;
            } else if (epi == EPI_P) {
                uint2 o;
                o.x = pack2(a[0], a[1]);
                o.y = pack2(a[2], a[3]);
                if (rok) *(uint2*)&((unsigned short*)out)[(size_t)row * 128 + col] = o;
            } else if (epi == EPI_ZR) {
                float4 bv = *(const float4*)&bias[col];
                float s0 = 1.f / (1.f + __expf(-(a[0] + bv.x)));
                float s1 = 1.f / (1.f + __expf(-(a[1] + bv.y)));
                float s2 = 1.f / (1.f + __expf(-(a[2] + bv.z)));
                float s3 = 1.f / (1.f + __expf(-(a[3] + bv.w)));
                if (col < 256) {
                    uint2 o; o.x = pack2(s0, s1); o.y = pack2(s2, s3);
                    if (rok) *(uint2*)&((unsigned short*)out)[(size_t)row * 256 + col] = o;
                } else {
                    int c2 = col - 256;
                    uint2 p4 = *(const uint2*)&xb1[(size_t)row * 256 + c2];
                    uint2 o;
                    o.x = pack2(bf2f(p4.x & 0xffffu) * s0, bf2f(p4.x >> 16) * s1);
                    o.y = pack2(bf2f(p4.y & 0xffffu) * s2, bf2f(p4.y >> 16) * s3);
                    if (rok) *(uint2*)&((unsigned short*)out2)[(size_t)row * 256 + c2] = o;
                }
            } else {  // EPI_H
                float4 bv = *(const float4*)&bias[col];
                uint2 z4 = *(const uint2*)&xb2[(size_t)row * 256 + col];
                uint2 p4 = *(const uint2*)&xb1[(size_t)row * 256 + col];
                float4 o;
                {
                    float s = a[0] + bv.x, e = __expf(2.f * s);
                    float ht = 1.f - 2.f / (e + 1.f);
                    float Zt = bf2f(z4.x & 0xffffu), ph = bf2f(p4.x & 0xffffu);
                    o.x = Zt * ph + (1.f - Zt) * ht;
                }
                {
                    float s = a[1] + bv.y, e = __expf(2.f * s);
                    float ht = 1.f - 2.f / (e + 1.f);
                    float Zt = bf2f(z4.x >> 16), ph = bf2f(p4.x >> 16);
                    o.y = Zt * ph + (1.f - Zt) * ht;
                }
                {
                    float s = a[2] + bv.z, e = __expf(2.f * s);
                    float ht = 1.f - 2.f / (e + 1.f);
                    float Zt = bf2f(z4.y & 0xffffu), ph = bf2f(p4.y & 0xffffu);
                    o.z = Zt * ph + (1.f - Zt) * ht;
                }
                {
                    float s = a[3] + bv.w, e = __expf(2.f * s);
                    float ht = 1.f - 2.f / (e + 1.f);
                    float Zt = bf2f(z4.y >> 16), ph = bf2f(p4.y >> 16);
                    o.w = Zt * ph + (1.f - Zt) * ht;
                }
                if (rok) *(float4*)&((float*)out)[(size_t)row * 256 + col] = o;
            }
        }
    }
}

// ---------------- launch ----------------

extern "C" void kernel_launch(void* const* d_in, const int* in_sizes, int n_in,
                              void* d_out, int out_size, void* d_ws, size_t ws_size,
                              hipStream_t stream) {
    const float* x      = (const float*)d_in[0];
    const int*   ei     = (const int*)d_in[1];
    const float* ew     = (const float*)d_in[2];
    const float* prev_h = (const float*)d_in[3];
    const float* W1  = (const float*)d_in[4];  const float* b1  = (const float*)d_in[5];
    const float* W2  = (const float*)d_in[6];  const float* b2  = (const float*)d_in[7];
    const float* Wxz = (const float*)d_in[8];  const float* bxz = (const float*)d_in[9];
    const float* Whz = (const float*)d_in[10]; const float* bhz = (const float*)d_in[11];
    const float* Wxr = (const float*)d_in[12]; const float* bxr = (const float*)d_in[13];
    const float* Whr = (const float*)d_in[14]; const float* bhr = (const float*)d_in[15];
    const float* Wxh = (const float*)d_in[16]; const float* bxh = (const float*)d_in[17];
    const float* Whh = (const float*)d_in[18]; const float* bhh = (const float*)d_in[19];
    const float* Whead = (const float*)d_in[20]; const float* bhead = (const float*)d_in[21];

    const int N = in_sizes[0] / 128;
    const int E = in_sizes[2];
    const int* esrc = ei;
    const int* edst = ei + E;

    float* ws = (float*)d_ws;
    size_t o = 0;
    float* dinv     = ws + o; o += (size_t)N;
    int*   cnt      = (int*)(ws + o); o += (size_t)N;
    int*   rowp     = (int*)(ws + o); o += (size_t)N + 4;
    int*   bsum     = (int*)(ws + o); o += 256;
    int*   csr_src  = (int*)(ws + o); o += (size_t)E;
    float* csr_norm = ws + o; o += (size_t)E;
    unsigned short* zx   = (unsigned short*)(ws + o); o += (size_t)N * 128;  // [N,256]: z | x
    unsigned short* phb  = (unsigned short*)(ws + o); o += (size_t)N * 128;  // prev_h bf16
    unsigned short* buf1 = (unsigned short*)(ws + o); o += (size_t)N * 128;  // t -> gw2 -> q
    unsigned short* Zbf  = (unsigned short*)(ws + o); o += (size_t)N * 128;  // g_bf -> Z bf16
    unsigned short* Bt1  = (unsigned short*)(ws + o); o += 16384;
    unsigned short* Bt2  = (unsigned short*)(ws + o); o += 16384;
    unsigned short* BtZR = (unsigned short*)(ws + o); o += 131072;
    unsigned short* BtH  = (unsigned short*)(ws + o); o += 65536;
    float* bZR      = ws + o; o += 512;
    float* bH       = ws + o; o += 256;
    float* zsum     = ws + o; o += 128;

    unsigned short* g_bf = Zbf;
    float* hout = (float*)d_out + 1;

    const int TPB = 256;
    int gE = (E + TPB - 1) / TPB;
    int gAgg = (N * 64 + TPB - 1) / TPB;
    int nb = (N + 127) / 128;
    int nsb = (N + 255) / 256;          // scan blocks (must be <= 256)

    // prep: deg/cnt init + x,prev_h -> bf16
    {
        long long tot = (long long)N * 97;
        prep_k<<<(int)((tot + TPB - 1) / TPB), TPB, 0, stream>>>(x, prev_h, dinv, cnt, zx, phb, N);
    }
    // weights + biases: 2*32768 + 6*65536 + 768 = 459520 threads
    {
        const int cvtw_total = 2 * 32768 + 6 * 65536 + 768;
        cvtwb_k<<<(cvtw_total + TPB - 1) / TPB, TPB, 0, stream>>>(
            W1, W2, Wxz, Whz, Wxr, Whr, Wxh, Whh,
            bxz, bhz, bxr, bhr, bxh, bhh, Bt1, Bt2, BtZR, BtH, bZR, bH);
    }

    // degree + CSR
    deg_cnt_k<<<gE, TPB, 0, stream>>>(edst, ew, dinv, cnt, E);
    dinv_k<<<(N + TPB - 1) / TPB, TPB, 0, stream>>>(dinv, N);
    scan1_k<<<nsb, 256, 0, stream>>>(cnt, bsum, N);
    scan2_k<<<1, 256, 0, stream>>>(bsum, nsb);
    scan3_k<<<nsb, 256, 0, stream>>>(cnt, bsum, rowp, N);
    fill_csr_k<<<gE, TPB, 0, stream>>>(esrc, edst, ew, dinv, cnt, csr_src, csr_norm, E);

    // t = agg(x)
    agg_bf_k<0><<<gAgg, TPB, 0, stream>>>(rowp, csr_src, csr_norm, zx, 128, 64, dinv,
                                          nullptr, buf1, 64, 0, N);

    // g = relu(t@W1 + b1) + prev_h
    mm_bf16_k<<<nb * 2, 512, 0, stream>>>(buf1, buf1, 128, 128, 128, Bt1, 128, N, 2,
                                          b1, phb, nullptr, g_bf, nullptr, EPI_G);
    // gw2 = g@W2
    mm_bf16_k<<<nb, 512, 0, stream>>>(g_bf, g_bf, 256, 256, 256, Bt2, 256, N, 1,
                                      nullptr, nullptr, nullptr, buf1, nullptr, EPI_P);
    // z = relu(agg(gw2) + b2)
    agg_bf_k<1><<<gAgg, TPB, 0, stream>>>(rowp, csr_src, csr_norm, buf1, 64, 0, dinv,
                                          b2, zx, 128, 0, N);

    // head
    hipMemsetAsync(zsum, 0, 128 * sizeof(float), stream);
    colsum_bf_k<<<512, 128, 0, stream>>>(zx, zsum, N);
    head_k<<<1, 128, 0, stream>>>(zsum, Whead, bhead, (float*)d_out, 1.0f / (float)N);

    // Z|R fused GEMM
    mm_bf16_k<<<nb * 4, 512, 0, stream>>>(zx, phb, 256, 256, 256, BtZR, 512, N, 4,
                                          bZR, phb, nullptr, Zbf, buf1, EPI_ZR);
    // h GEMM
    mm_bf16_k<<<nb * 2, 512, 0, stream>>>(zx, buf1, 256, 256, 256, BtH, 512, N, 2,
                                          bH, phb, Zbf, hout, nullptr, EPI_H);
}

// Round 12
// 415.472 us; speedup vs baseline: 1.3731x; 1.1228x over previous
//
#include <hip/hip_runtime.h>
#include <math.h>

typedef __attribute__((ext_vector_type(8))) short short8;   // 8 bf16 = 4 VGPR
typedef __attribute__((ext_vector_type(4))) float f32x4;

__device__ inline unsigned short f2bf(float f) {
    unsigned int u = __float_as_uint(f);
    u += 0x7fffu + ((u >> 16) & 1u);          // RNE
    return (unsigned short)(u >> 16);
}
__device__ inline float bf2f(unsigned int h) { return __uint_as_float(h << 16); }
__device__ inline unsigned pack2(float a, float b) {
    return (unsigned)f2bf(a) | ((unsigned)f2bf(b) << 16);
}

#define GLOAD_LDS16(gp, lp)                                                              \
    __builtin_amdgcn_global_load_lds(                                                    \
        (const __attribute__((address_space(1))) unsigned int*)(const void*)(gp),        \
        (__attribute__((address_space(3))) unsigned int*)(void*)(lp), 16, 0, 0)

// ---------------- fused prep: deg/cnt init + x->bf16 + prev_h->bf16 + zsum=0 ----------------

__global__ void prep_k(const float* __restrict__ x, const float* __restrict__ ph,
                       float* __restrict__ deg, int* __restrict__ cnt,
                       unsigned short* __restrict__ zx, unsigned short* __restrict__ phb,
                       float* __restrict__ zsum, int N) {
    int t = blockIdx.x * blockDim.x + threadIdx.x;
    if (t < N) { deg[t] = 1.0f; cnt[t] = 0; return; }
    t -= N;
    if (t < N * 32) {           // cvt_x -> zx cols 128..255
        int r = t >> 5, c4 = (t & 31) * 4;
        float4 v = *(const float4*)&x[(size_t)r * 128 + c4];
        uint2 o; o.x = pack2(v.x, v.y); o.y = pack2(v.z, v.w);
        *(uint2*)&zx[(size_t)r * 256 + 128 + c4] = o;
        return;
    }
    t -= N * 32;
    if (t < N * 64) {           // cvt_ph
        int r = t >> 6, c4 = (t & 63) * 4;
        float4 v = *(const float4*)&ph[(size_t)r * 256 + c4];
        uint2 o; o.x = pack2(v.x, v.y); o.y = pack2(v.z, v.w);
        *(uint2*)&phb[(size_t)r * 256 + c4] = o;
        return;
    }
    t -= N * 64;
    if (t < 128) zsum[t] = 0.f;
}

// ---------------- weights -> bf16 transposed + fused biases ----------------
// thread space: 32768 (W1) + 32768 (W2) + 6*65536 + 768 (biases) = 459520

__global__ void cvtwb_k(const float* W1, const float* W2,
                        const float* Wxz, const float* Whz, const float* Wxr, const float* Whr,
                        const float* Wxh, const float* Whh,
                        const float* bxz, const float* bhz, const float* bxr, const float* bhr,
                        const float* bxh, const float* bhh,
                        unsigned short* Bt1, unsigned short* Bt2,
                        unsigned short* BtZR, unsigned short* BtH,
                        float* bZR, float* bH) {
    int t = blockIdx.x * blockDim.x + threadIdx.x;
    if (t < 32768) { int k = t >> 8, n = t & 255; Bt1[(size_t)n * 128 + k] = f2bf(W1[t]); return; }
    t -= 32768;
    if (t < 32768) { int k = t >> 7, n = t & 127; Bt2[(size_t)n * 256 + k] = f2bf(W2[t]); return; }
    t -= 32768;
    if (t < 65536) { int k = t >> 8, n = t & 255; BtZR[(size_t)n * 512 + k] = f2bf(Wxz[t]); return; }
    t -= 65536;
    if (t < 65536) { int k = t >> 8, n = t & 255; BtZR[(size_t)n * 512 + 256 + k] = f2bf(Whz[t]); return; }
    t -= 65536;
    if (t < 65536) { int k = t >> 8, n = t & 255; BtZR[(size_t)(256 + n) * 512 + k] = f2bf(Wxr[t]); return; }
    t -= 65536;
    if (t < 65536) { int k = t >> 8, n = t & 255; BtZR[(size_t)(256 + n) * 512 + 256 + k] = f2bf(Whr[t]); return; }
    t -= 65536;
    if (t < 65536) { int k = t >> 8, n = t & 255; BtH[(size_t)n * 512 + k] = f2bf(Wxh[t]); return; }
    t -= 65536;
    if (t < 65536) { int k = t >> 8, n = t & 255; BtH[(size_t)n * 512 + 256 + k] = f2bf(Whh[t]); return; }
    t -= 65536;
    if (t < 256)       bZR[t] = bxz[t] + bhz[t];
    else if (t < 512)  bZR[t] = bxr[t - 256] + bhr[t - 256];
    else if (t < 768)  bH[t - 512] = bxh[t - 512] + bhh[t - 512];
}

// ---------------- degree / CSR ----------------

__global__ void deg_cnt_k(const int* __restrict__ dst, const float* __restrict__ w,
                          float* deg, int* cnt, int E) {
    int e = blockIdx.x * blockDim.x + threadIdx.x;
    if (e < E) { int d = dst[e]; atomicAdd(&deg[d], w[e]); atomicAdd(&cnt[d], 1); }
}

// scan1 + dinv fused (deg ready after deg_cnt_k)
__global__ void scan1_k(const int* __restrict__ cnt, int* __restrict__ bsum,
                        float* __restrict__ deg, int N) {
    __shared__ int ws_[4];
    int b = blockIdx.x, t = threadIdx.x;
    int i = b * 256 + t;
    if (i < N) { float d = deg[i]; deg[i] = d > 0.f ? rsqrtf(d) : 0.f; }
    int v = (i < N) ? cnt[i] : 0;
    int lane = t & 63, wv = t >> 6;
    #pragma unroll
    for (int o = 1; o < 64; o <<= 1) { int u = __shfl_up(v, o, 64); if (lane >= o) v += u; }
    if (lane == 63) ws_[wv] = v;
    __syncthreads();
    if (t == 0) bsum[b] = ws_[0] + ws_[1] + ws_[2] + ws_[3];
}

__global__ void scan2_k(int* __restrict__ bsum, int nb) {
    __shared__ int ws_[4];
    int t = threadIdx.x;
    int v = (t < nb) ? bsum[t] : 0;
    int orig = v;
    int lane = t & 63, wv = t >> 6;
    #pragma unroll
    for (int o = 1; o < 64; o <<= 1) { int u = __shfl_up(v, o, 64); if (lane >= o) v += u; }
    if (lane == 63) ws_[wv] = v;
    __syncthreads();
    int add = 0;
    for (int k = 0; k < wv; ++k) add += ws_[k];
    if (t < nb) bsum[t] = v + add - orig;     // exclusive block offset
}

__global__ void scan3_k(int* __restrict__ cnt, const int* __restrict__ bsum,
                        int* __restrict__ rp, int N) {
    __shared__ int ws_[4];
    int b = blockIdx.x, t = threadIdx.x;
    int i = b * 256 + t;
    int v = (i < N) ? cnt[i] : 0;
    int orig = v;
    int lane = t & 63, wv = t >> 6;
    #pragma unroll
    for (int o = 1; o < 64; o <<= 1) { int u = __shfl_up(v, o, 64); if (lane >= o) v += u; }
    if (lane == 63) ws_[wv] = v;
    __syncthreads();
    int add = bsum[b];
    for (int k = 0; k < wv; ++k) add += ws_[k];
    int incl = v + add;
    if (i < N) {
        rp[i + 1] = incl;
        cnt[i] = incl - orig;                 // exclusive -> fill cursor
        if (i == 0) rp[0] = 0;
    }
}

__global__ void fill_csr_k(const int* __restrict__ src, const int* __restrict__ dst,
                           const float* __restrict__ w, const float* __restrict__ dinv,
                           int* ofs, int* __restrict__ csr_src, float* __restrict__ csr_norm, int E) {
    int e = blockIdx.x * blockDim.x + threadIdx.x;
    if (e < E) {
        int s = src[e], d = dst[e];
        int p = atomicAdd(&ofs[d], 1);
        csr_src[p] = s;
        csr_norm[p] = dinv[s] * w[e] * dinv[d];
    }
}

// ---------------- CSR gather, 2 edges/iter (bf16 in, f32 accum, bf16 out) ----------------
template <int EPI>
__global__ void agg_bf_k(const int* __restrict__ rp, const int* __restrict__ cs,
                         const float* __restrict__ cn,
                         const unsigned short* __restrict__ X, int ldx2, int xo2,
                         const float* __restrict__ dinv, const float* __restrict__ bias,
                         unsigned short* __restrict__ Y, int ldy2, int yo2, int N) {
    int wid = (blockIdx.x * blockDim.x + threadIdx.x) >> 6;
    int lane = threadIdx.x & 63;
    if (wid >= N) return;
    const unsigned int* Xu = (const unsigned int*)X;
    int h = lane >> 5, c = lane & 31;

    float dv = dinv[wid]; dv *= dv;
    float w0 = h ? 0.f : dv;                   // self-loop only on even half
    uint2 sv = *(const uint2*)&Xu[(size_t)wid * ldx2 + xo2 + c * 2];
    float a0 = bf2f(sv.x & 0xffffu) * w0, a1 = bf2f(sv.x >> 16) * w0;
    float a2 = bf2f(sv.y & 0xffffu) * w0, a3 = bf2f(sv.y >> 16) * w0;

    int p = rp[wid], pe = rp[wid + 1];
    for (; p + 4 <= pe; p += 4) {              // 4 edges = 2 pairs
        int sA = cs[p + h];      float nA = cn[p + h];
        int sB = cs[p + 2 + h];  float nB = cn[p + 2 + h];
        uint2 vA = *(const uint2*)&Xu[(size_t)sA * ldx2 + xo2 + c * 2];
        uint2 vB = *(const uint2*)&Xu[(size_t)sB * ldx2 + xo2 + c * 2];
        a0 = fmaf(bf2f(vA.x & 0xffffu), nA, a0); a1 = fmaf(bf2f(vA.x >> 16), nA, a1);
        a2 = fmaf(bf2f(vA.y & 0xffffu), nA, a2); a3 = fmaf(bf2f(vA.y >> 16), nA, a3);
        a0 = fmaf(bf2f(vB.x & 0xffffu), nB, a0); a1 = fmaf(bf2f(vB.x >> 16), nB, a1);
        a2 = fmaf(bf2f(vB.y & 0xffffu), nB, a2); a3 = fmaf(bf2f(vB.y >> 16), nB, a3);
    }
    if (p + 2 <= pe) {                         // one pair
        int s = cs[p + h]; float nv = cn[p + h];
        uint2 v = *(const uint2*)&Xu[(size_t)s * ldx2 + xo2 + c * 2];
        a0 = fmaf(bf2f(v.x & 0xffffu), nv, a0); a1 = fmaf(bf2f(v.x >> 16), nv, a1);
        a2 = fmaf(bf2f(v.y & 0xffffu), nv, a2); a3 = fmaf(bf2f(v.y >> 16), nv, a3);
        p += 2;
    }
    if (p < pe) {                              // odd tail: even half only
        int s = cs[p]; float nv = h ? 0.f : cn[p];
        uint2 v = *(const uint2*)&Xu[(size_t)s * ldx2 + xo2 + c * 2];
        a0 = fmaf(bf2f(v.x & 0xffffu), nv, a0); a1 = fmaf(bf2f(v.x >> 16), nv, a1);
        a2 = fmaf(bf2f(v.y & 0xffffu), nv, a2); a3 = fmaf(bf2f(v.y >> 16), nv, a3);
    }

    a0 += __shfl_xor(a0, 32);
    a1 += __shfl_xor(a1, 32);
    a2 += __shfl_xor(a2, 32);
    a3 += __shfl_xor(a3, 32);

    if (EPI == 1) {
        float4 bv = *(const float4*)&bias[c * 4];
        a0 = fmaxf(a0 + bv.x, 0.f); a1 = fmaxf(a1 + bv.y, 0.f);
        a2 = fmaxf(a2 + bv.z, 0.f); a3 = fmaxf(a3 + bv.w, 0.f);
    }
    if (h == 0) {
        uint2 o; o.x = pack2(a0, a1); o.y = pack2(a2, a3);
        *(uint2*)&((unsigned int*)Y)[(size_t)wid * ldy2 + yo2 + c * 2] = o;
    }
}

// ---------------- head: coalesced column sum ----------------
// 256 threads: 32 threads cover one z row (uint2 = 4 bf16 cols each); 8 rows/pass.

__global__ void colsum_bf_k(const unsigned short* __restrict__ Z, float* zsum, int N) {
    __shared__ float red[8][128];
    int t = threadIdx.x;
    int rg = t >> 5, c4 = (t & 31) * 4;
    int rpb = (N + gridDim.x - 1) / gridDim.x;
    int r0 = blockIdx.x * rpb, r1 = min(N, r0 + rpb);
    float s0 = 0.f, s1 = 0.f, s2 = 0.f, s3 = 0.f;
    for (int r = r0 + rg; r < r1; r += 8) {
        uint2 v = *(const uint2*)&Z[(size_t)r * 256 + c4];
        s0 += bf2f(v.x & 0xffffu); s1 += bf2f(v.x >> 16);
        s2 += bf2f(v.y & 0xffffu); s3 += bf2f(v.y >> 16);
    }
    red[rg][c4] = s0; red[rg][c4 + 1] = s1; red[rg][c4 + 2] = s2; red[rg][c4 + 3] = s3;
    __syncthreads();
    if (t < 128) {
        float s = 0.f;
        #pragma unroll
        for (int k = 0; k < 8; ++k) s += red[k][t];
        atomicAdd(&zsum[t], s);
    }
}

__global__ void head_k(const float* __restrict__ zsum, const float* __restrict__ Wh,
                       const float* __restrict__ bh, float* __restrict__ out, float invN) {
    __shared__ float red[128];
    int c = threadIdx.x;
    red[c] = zsum[c] * invN * Wh[c];
    __syncthreads();
    for (int s = 64; s > 0; s >>= 1) {
        if (c < s) red[c] += red[c + s];
        __syncthreads();
    }
    if (c == 0) out[0] = red[0] + bh[0];
}

// ---------------- bf16 MFMA GEMM, 128x128 tile, 512 threads, BK=64 ----------------
// Double-buffered LDS (A:16KB + B:16KB per buf), 4 global_load_lds/thread/step,
// counted vmcnt(4). LDS layout [row][8 slots of 16B], slot swizzle ^(row&7).
// 16 MFMAs/wave/step (kk=0,1 x 2 ms x 4 ns). Transposed-acc epilogue.

enum { EPI_G = 0, EPI_P = 1, EPI_ZR = 2, EPI_H = 3 };

__global__ __launch_bounds__(512)
void mm_bf16_k(const unsigned short* __restrict__ A0, const unsigned short* __restrict__ A1,
               int lda0, int lda1, int kb,
               const unsigned short* __restrict__ Bt, int K, int M, int ncb,
               const float* __restrict__ bias,
               const unsigned short* __restrict__ xb1, const unsigned short* __restrict__ xb2,
               void* __restrict__ out, void* __restrict__ out2, int epi)
{
    __shared__ unsigned short Als[2][8192];   // [buf][128 rows x 64 k]
    __shared__ unsigned short Bls[2][8192];

    // XCD-bijective swizzle, bcol fast
    int nwg = gridDim.x;
    int bid = blockIdx.x;
    int q = nwg >> 3, r = nwg & 7;
    int xcd = bid & 7;
    int wg = (xcd < r ? xcd * (q + 1) : r * (q + 1) + (xcd - r) * q) + (bid >> 3);
    int brow = wg / ncb, bcol = wg - brow * ncb;
    int row0 = brow * 128, col0 = bcol * 128;

    int t = threadIdx.x;
    int w = t >> 6, lane = t & 63;
    int wr = w >> 1, wc = w & 1;
    int m15 = lane & 15, g = lane >> 4;

    f32x4 acc[2][4];
    #pragma unroll
    for (int i = 0; i < 2; ++i)
        #pragma unroll
        for (int j = 0; j < 4; ++j)
            #pragma unroll
            for (int qq = 0; qq < 4; ++qq) acc[i][j][qq] = 0.f;

    // staging: pass i: chunk idx = i*512 + t; row = idx>>3, slot = idx&7;
    // global k-slot = slot ^ (row&7); LDS linear dest (wave-uniform base + lane*16).
    auto stage = [&](int buf, int kt) {
        const unsigned short* Ap = A0; int lda = lda0; int ka = kt;
        if (kt >= kb) { Ap = A1; lda = lda1; ka = kt - kb; }
        #pragma unroll
        for (int i = 0; i < 2; ++i) {
            int idx = i * 512 + t;
            int row = idx >> 3, slot = idx & 7;
            int gk = (slot ^ (row & 7)) * 8;
            int gr = row0 + row; gr = gr < M ? gr : M - 1;
            GLOAD_LDS16(&Ap[(size_t)gr * lda + ka + gk], &Als[buf][(size_t)(i * 512 + w * 64) * 8]);
            GLOAD_LDS16(&Bt[(size_t)(col0 + row) * K + kt + gk], &Bls[buf][(size_t)(i * 512 + w * 64) * 8]);
        }
    };

    int NT = K >> 6;            // K in {128,256,512} -> 2,4,8
    stage(0, 0);
    int pb = 0;

    for (int ti = 0; ti < NT; ++ti) {
        if (ti + 1 < NT) {
            stage(pb ^ 1, (ti + 1) << 6);
            asm volatile("s_waitcnt vmcnt(4)" ::: "memory");
        } else {
            asm volatile("s_waitcnt vmcnt(0)" ::: "memory");
        }
        __builtin_amdgcn_s_barrier();
        __builtin_amdgcn_sched_barrier(0);

        short8 af[2][2], bfr[2][4];
        #pragma unroll
        for (int kk = 0; kk < 2; ++kk) {
            #pragma unroll
            for (int ms = 0; ms < 2; ++ms) {
                int rt = wr * 32 + ms * 16 + m15;
                af[kk][ms] = *(const short8*)&Als[pb][rt * 64 + (((kk * 4 + g) ^ (rt & 7)) << 3)];
            }
            #pragma unroll
            for (int ns = 0; ns < 4; ++ns) {
                int nt = wc * 64 + ns * 16 + m15;
                bfr[kk][ns] = *(const short8*)&Bls[pb][nt * 64 + (((kk * 4 + g) ^ (nt & 7)) << 3)];
            }
        }
        asm volatile("s_waitcnt lgkmcnt(0)" ::: "memory");
        __builtin_amdgcn_sched_barrier(0);
        __builtin_amdgcn_s_barrier();

        #pragma unroll
        for (int kk = 0; kk < 2; ++kk)
            #pragma unroll
            for (int ms = 0; ms < 2; ++ms)
                #pragma unroll
                for (int ns = 0; ns < 4; ++ns)
                    acc[ms][ns] = __builtin_amdgcn_mfma_f32_16x16x32_bf16(bfr[kk][ns], af[kk][ms], acc[ms][ns], 0, 0, 0);
        pb ^= 1;
    }

    // epilogue: row = row0 + wr*32 + ms*16 + m15 ; cols = col0 + wc*64 + ns*16 + g*4 + (0..3)
    #pragma unroll
    for (int ms = 0; ms < 2; ++ms) {
        int row = row0 + wr * 32 + ms * 16 + m15;
        bool rok = row < M;
        #pragma unroll
        for (int ns = 0; ns < 4; ++ns) {
            int col = col0 + wc * 64 + ns * 16 + g * 4;
            f32x4 a = acc[ms][ns];
            if (epi == EPI_G) {
                float4 bv = *(const float4*)&bias[col];
                uint2 p4 = *(const uint2*)&xb1[(size_t)row * 256 + col];
                uint2 o;
                o.x = pack2(fmaxf(a[0] + bv.x, 0.f) + bf2f(p4.x & 0xffffu),
                            fmaxf(a[1] + bv.y, 0.f) + bf2f(p4.x >> 16));
                o.y = pack2(fmaxf(a[2] + bv.z, 0.f) + bf2f(p4.y & 0xffffu),
                            fmaxf(a[3] + bv.w, 0.f) + bf2f(p4.y >> 16));
                if (rok) *(uint2*)&((unsigned short*)out)[(size_t)row * 256 + col] = o;
            } else if (epi == EPI_P) {
                uint2 o;
                o.x = pack2(a[0], a[1]);
                o.y = pack2(a[2], a[3]);
                if (rok) *(uint2*)&((unsigned short*)out)[(size_t)row * 128 + col] = o;
            } else if (epi == EPI_ZR) {
                float4 bv = *(const float4*)&bias[col];
                float s0 = 1.f / (1.f + __expf(-(a[0] + bv.x)));
                float s1 = 1.f / (1.f + __expf(-(a[1] + bv.y)));
                float s2 = 1.f / (1.f + __expf(-(a[2] + bv.z)));
                float s3 = 1.f / (1.f + __expf(-(a[3] + bv.w)));
                if (col < 256) {
                    uint2 o; o.x = pack2(s0, s1); o.y = pack2(s2, s3);
                    if (rok) *(uint2*)&((unsigned short*)out)[(size_t)row * 256 + col] = o;
                } else {
                    int c2 = col - 256;
                    uint2 p4 = *(const uint2*)&xb1[(size_t)row * 256 + c2];
                    uint2 o;
                    o.x = pack2(bf2f(p4.x & 0xffffu) * s0, bf2f(p4.x >> 16) * s1);
                    o.y = pack2(bf2f(p4.y & 0xffffu) * s2, bf2f(p4.y >> 16) * s3);
                    if (rok) *(uint2*)&((unsigned short*)out2)[(size_t)row * 256 + c2] = o;
                }
            } else {  // EPI_H
                float4 bv = *(const float4*)&bias[col];
                uint2 z4 = *(const uint2*)&xb2[(size_t)row * 256 + col];
                uint2 p4 = *(const uint2*)&xb1[(size_t)row * 256 + col];
                float4 o;
                {
                    float s = a[0] + bv.x, e = __expf(2.f * s);
                    float ht = 1.f - 2.f / (e + 1.f);
                    float Zt = bf2f(z4.x & 0xffffu), ph = bf2f(p4.x & 0xffffu);
                    o.x = Zt * ph + (1.f - Zt) * ht;
                }
                {
                    float s = a[1] + bv.y, e = __expf(2.f * s);
                    float ht = 1.f - 2.f / (e + 1.f);
                    float Zt = bf2f(z4.x >> 16), ph = bf2f(p4.x >> 16);
                    o.y = Zt * ph + (1.f - Zt) * ht;
                }
                {
                    float s = a[2] + bv.z, e = __expf(2.f * s);
                    float ht = 1.f - 2.f / (e + 1.f);
                    float Zt = bf2f(z4.y & 0xffffu), ph = bf2f(p4.y & 0xffffu);
                    o.z = Zt * ph + (1.f - Zt) * ht;
                }
                {
                    float s = a[3] + bv.w, e = __expf(2.f * s);
                    float ht = 1.f - 2.f / (e + 1.f);
                    float Zt = bf2f(z4.y >> 16), ph = bf2f(p4.y >> 16);
                    o.w = Zt * ph + (1.f - Zt) * ht;
                }
                if (rok) *(float4*)&((float*)out)[(size_t)row * 256 + col] = o;
            }
        }
    }
}

// ---------------- launch ----------------

extern "C" void kernel_launch(void* const* d_in, const int* in_sizes, int n_in,
                              void* d_out, int out_size, void* d_ws, size_t ws_size,
                              hipStream_t stream) {
    const float* x      = (const float*)d_in[0];
    const int*   ei     = (const int*)d_in[1];
    const float* ew     = (const float*)d_in[2];
    const float* prev_h = (const float*)d_in[3];
    const float* W1  = (const float*)d_in[4];  const float* b1  = (const float*)d_in[5];
    const float* W2  = (const float*)d_in[6];  const float* b2  = (const float*)d_in[7];
    const float* Wxz = (const float*)d_in[8];  const float* bxz = (const float*)d_in[9];
    const float* Whz = (const float*)d_in[10]; const float* bhz = (const float*)d_in[11];
    const float* Wxr = (const float*)d_in[12]; const float* bxr = (const float*)d_in[13];
    const float* Whr = (const float*)d_in[14]; const float* bhr = (const float*)d_in[15];
    const float* Wxh = (const float*)d_in[16]; const float* bxh = (const float*)d_in[17];
    const float* Whh = (const float*)d_in[18]; const float* bhh = (const float*)d_in[19];
    const float* Whead = (const float*)d_in[20]; const float* bhead = (const float*)d_in[21];

    const int N = in_sizes[0] / 128;
    const int E = in_sizes[2];
    const int* esrc = ei;
    const int* edst = ei + E;

    float* ws = (float*)d_ws;
    size_t o = 0;
    float* dinv     = ws + o; o += (size_t)N;
    int*   cnt      = (int*)(ws + o); o += (size_t)N;
    int*   rowp     = (int*)(ws + o); o += (size_t)N + 4;
    int*   bsum     = (int*)(ws + o); o += 256;
    int*   csr_src  = (int*)(ws + o); o += (size_t)E;
    float* csr_norm = ws + o; o += (size_t)E;
    unsigned short* zx   = (unsigned short*)(ws + o); o += (size_t)N * 128;  // [N,256]: z | x
    unsigned short* phb  = (unsigned short*)(ws + o); o += (size_t)N * 128;  // prev_h bf16
    unsigned short* buf1 = (unsigned short*)(ws + o); o += (size_t)N * 128;  // t -> gw2 -> q
    unsigned short* Zbf  = (unsigned short*)(ws + o); o += (size_t)N * 128;  // g_bf -> Z bf16
    unsigned short* Bt1  = (unsigned short*)(ws + o); o += 16384;
    unsigned short* Bt2  = (unsigned short*)(ws + o); o += 16384;
    unsigned short* BtZR = (unsigned short*)(ws + o); o += 131072;
    unsigned short* BtH  = (unsigned short*)(ws + o); o += 65536;
    float* bZR      = ws + o; o += 512;
    float* bH       = ws + o; o += 256;
    float* zsum     = ws + o; o += 128;

    unsigned short* g_bf = Zbf;
    float* hout = (float*)d_out + 1;

    const int TPB = 256;
    int gE = (E + TPB - 1) / TPB;
    int gAgg = (N * 64 + TPB - 1) / TPB;
    int nb = (N + 127) / 128;
    int nsb = (N + 255) / 256;          // scan blocks (must be <= 256)

    // prep: deg/cnt init + x,prev_h -> bf16 + zsum=0
    {
        long long tot = (long long)N * 97 + 128;
        prep_k<<<(int)((tot + TPB - 1) / TPB), TPB, 0, stream>>>(x, prev_h, dinv, cnt, zx, phb, zsum, N);
    }
    // weights + biases
    {
        const int cvtw_total = 2 * 32768 + 6 * 65536 + 768;
        cvtwb_k<<<(cvtw_total + TPB - 1) / TPB, TPB, 0, stream>>>(
            W1, W2, Wxz, Whz, Wxr, Whr, Wxh, Whh,
            bxz, bhz, bxr, bhr, bxh, bhh, Bt1, Bt2, BtZR, BtH, bZR, bH);
    }

    // degree + CSR
    deg_cnt_k<<<gE, TPB, 0, stream>>>(edst, ew, dinv, cnt, E);
    scan1_k<<<nsb, 256, 0, stream>>>(cnt, bsum, dinv, N);     // + dinv fused
    scan2_k<<<1, 256, 0, stream>>>(bsum, nsb);
    scan3_k<<<nsb, 256, 0, stream>>>(cnt, bsum, rowp, N);
    fill_csr_k<<<gE, TPB, 0, stream>>>(esrc, edst, ew, dinv, cnt, csr_src, csr_norm, E);

    // t = agg(x)
    agg_bf_k<0><<<gAgg, TPB, 0, stream>>>(rowp, csr_src, csr_norm, zx, 128, 64, dinv,
                                          nullptr, buf1, 64, 0, N);

    // g = relu(t@W1 + b1) + prev_h
    mm_bf16_k<<<nb * 2, 512, 0, stream>>>(buf1, buf1, 128, 128, 128, Bt1, 128, N, 2,
                                          b1, phb, nullptr, g_bf, nullptr, EPI_G);
    // gw2 = g@W2
    mm_bf16_k<<<nb, 512, 0, stream>>>(g_bf, g_bf, 256, 256, 256, Bt2, 256, N, 1,
                                      nullptr, nullptr, nullptr, buf1, nullptr, EPI_P);
    // z = relu(agg(gw2) + b2)
    agg_bf_k<1><<<gAgg, TPB, 0, stream>>>(rowp, csr_src, csr_norm, buf1, 64, 0, dinv,
                                          b2, zx, 128, 0, N);

    // head
    colsum_bf_k<<<256, 256, 0, stream>>>(zx, zsum, N);
    head_k<<<1, 128, 0, stream>>>(zsum, Whead, bhead, (float*)d_out, 1.0f / (float)N);

    // Z|R fused GEMM
    mm_bf16_k<<<nb * 4, 512, 0, stream>>>(zx, phb, 256, 256, 256, BtZR, 512, N, 4,
                                          bZR, phb, nullptr, Zbf, buf1, EPI_ZR);
    // h GEMM
    mm_bf16_k<<<nb * 2, 512, 0, stream>>>(zx, buf1, 256, 256, 256, BtH, 512, N, 2,
                                          bH, phb, Zbf, hout, nullptr, EPI_H);
}

// Round 13
// 370.285 us; speedup vs baseline: 1.5407x; 1.1220x over previous
//
#include <hip/hip_runtime.h>
#include <math.h>

typedef __attribute__((ext_vector_type(8))) short short8;   // 8 bf16 = 4 VGPR
typedef __attribute__((ext_vector_type(4))) float f32x4;

__device__ inline unsigned short f2bf(float f) {
    unsigned int u = __float_as_uint(f);
    u += 0x7fffu + ((u >> 16) & 1u);          // RNE
    return (unsigned short)(u >> 16);
}
__device__ inline float bf2f(unsigned int h) { return __uint_as_float(h << 16); }
__device__ inline unsigned pack2(float a, float b) {
    return (unsigned)f2bf(a) | ((unsigned)f2bf(b) << 16);
}

#define GLOAD_LDS16(gp, lp)                                                              \
    __builtin_amdgcn_global_load_lds(                                                    \
        (const __attribute__((address_space(1))) unsigned int*)(const void*)(gp),        \
        (__attribute__((address_space(3))) unsigned int*)(void*)(lp), 16, 0, 0)

// ---------------- fused prep: cnt64 zero + x->bf16 + prev_h->bf16 + zsum=0 ----------------
// thread space: 2N (cnt64 zero as ints) + 32N (x) + 64N (ph) + 128 (zsum)

__global__ void prep_k(const float* __restrict__ x, const float* __restrict__ ph,
                       unsigned long long* __restrict__ cnt64,
                       unsigned short* __restrict__ zx, unsigned short* __restrict__ phb,
                       float* __restrict__ zsum, int N) {
    int t = blockIdx.x * blockDim.x + threadIdx.x;
    if (t < 2 * N) { ((int*)cnt64)[t] = 0; return; }
    t -= 2 * N;
    if (t < N * 32) {           // cvt_x -> zx cols 128..255
        int r = t >> 5, c4 = (t & 31) * 4;
        float4 v = *(const float4*)&x[(size_t)r * 128 + c4];
        uint2 o; o.x = pack2(v.x, v.y); o.y = pack2(v.z, v.w);
        *(uint2*)&zx[(size_t)r * 256 + 128 + c4] = o;
        return;
    }
    t -= N * 32;
    if (t < N * 64) {           // cvt_ph
        int r = t >> 6, c4 = (t & 63) * 4;
        float4 v = *(const float4*)&ph[(size_t)r * 256 + c4];
        uint2 o; o.x = pack2(v.x, v.y); o.y = pack2(v.z, v.w);
        *(uint2*)&phb[(size_t)r * 256 + c4] = o;
        return;
    }
    t -= N * 64;
    if (t < 128) zsum[t] = 0.f;
}

// ---------------- weights -> bf16 transposed + fused biases ----------------
// thread space: 32768 (W1) + 32768 (W2) + 6*65536 + 768 (biases) = 459520

__global__ void cvtwb_k(const float* W1, const float* W2,
                        const float* Wxz, const float* Whz, const float* Wxr, const float* Whr,
                        const float* Wxh, const float* Whh,
                        const float* bxz, const float* bhz, const float* bxr, const float* bhr,
                        const float* bxh, const float* bhh,
                        unsigned short* Bt1, unsigned short* Bt2,
                        unsigned short* BtZR, unsigned short* BtH,
                        float* bZR, float* bH) {
    int t = blockIdx.x * blockDim.x + threadIdx.x;
    if (t < 32768) { int k = t >> 8, n = t & 255; Bt1[(size_t)n * 128 + k] = f2bf(W1[t]); return; }
    t -= 32768;
    if (t < 32768) { int k = t >> 7, n = t & 127; Bt2[(size_t)n * 256 + k] = f2bf(W2[t]); return; }
    t -= 32768;
    if (t < 65536) { int k = t >> 8, n = t & 255; BtZR[(size_t)n * 512 + k] = f2bf(Wxz[t]); return; }
    t -= 65536;
    if (t < 65536) { int k = t >> 8, n = t & 255; BtZR[(size_t)n * 512 + 256 + k] = f2bf(Whz[t]); return; }
    t -= 65536;
    if (t < 65536) { int k = t >> 8, n = t & 255; BtZR[(size_t)(256 + n) * 512 + k] = f2bf(Wxr[t]); return; }
    t -= 65536;
    if (t < 65536) { int k = t >> 8, n = t & 255; BtZR[(size_t)(256 + n) * 512 + 256 + k] = f2bf(Whr[t]); return; }
    t -= 65536;
    if (t < 65536) { int k = t >> 8, n = t & 255; BtH[(size_t)n * 512 + k] = f2bf(Wxh[t]); return; }
    t -= 65536;
    if (t < 65536) { int k = t >> 8, n = t & 255; BtH[(size_t)n * 512 + 256 + k] = f2bf(Whh[t]); return; }
    t -= 65536;
    if (t < 256)       bZR[t] = bxz[t] + bhz[t];
    else if (t < 512)  bZR[t] = bxr[t - 256] + bhr[t - 256];
    else if (t < 768)  bH[t - 512] = bxh[t - 512] + bhh[t - 512];
}

// ---------------- degree+count: ONE u64 atomic per edge ----------------
// hi 32 bits: count; lo 32 bits: sum of w in 24-bit fixed point (w in [0,1)).

__global__ void deg_cnt_k(const int* __restrict__ dst, const float* __restrict__ w,
                          unsigned long long* cnt64, int E) {
    int e = blockIdx.x * blockDim.x + threadIdx.x;
    if (e < E) {
        unsigned wfix = __float2uint_rn(w[e] * 16777216.0f);
        atomicAdd(&cnt64[dst[e]], (1ULL << 32) | (unsigned long long)wfix);
    }
}

// scan1: decode cnt64 -> cnt (hi) + dinv (1 + lo/2^24); block sums for scan
__global__ void scan1_k(const unsigned long long* __restrict__ cnt64, int* __restrict__ bsum,
                        float* __restrict__ dinv, int N) {
    __shared__ int ws_[4];
    int b = blockIdx.x, t = threadIdx.x;
    int i = b * 256 + t;
    unsigned long long v64 = (i < N) ? cnt64[i] : 0ULL;
    if (i < N) {
        float deg = 1.0f + (float)(unsigned)(v64 & 0xffffffffu) * (1.0f / 16777216.0f);
        dinv[i] = rsqrtf(deg);                 // deg >= 1 always
    }
    int v = (int)(v64 >> 32);
    int lane = t & 63, wv = t >> 6;
    #pragma unroll
    for (int o = 1; o < 64; o <<= 1) { int u = __shfl_up(v, o, 64); if (lane >= o) v += u; }
    if (lane == 63) ws_[wv] = v;
    __syncthreads();
    if (t == 0) bsum[b] = ws_[0] + ws_[1] + ws_[2] + ws_[3];
}

__global__ void scan2_k(int* __restrict__ bsum, int nb) {
    __shared__ int ws_[4];
    int t = threadIdx.x;
    int v = (t < nb) ? bsum[t] : 0;
    int orig = v;
    int lane = t & 63, wv = t >> 6;
    #pragma unroll
    for (int o = 1; o < 64; o <<= 1) { int u = __shfl_up(v, o, 64); if (lane >= o) v += u; }
    if (lane == 63) ws_[wv] = v;
    __syncthreads();
    int add = 0;
    for (int k = 0; k < wv; ++k) add += ws_[k];
    if (t < nb) bsum[t] = v + add - orig;     // exclusive block offset
}

__global__ void scan3_k(const unsigned long long* __restrict__ cnt64, const int* __restrict__ bsum,
                        int* __restrict__ rp, int* __restrict__ cur, int N) {
    __shared__ int ws_[4];
    int b = blockIdx.x, t = threadIdx.x;
    int i = b * 256 + t;
    int v = (i < N) ? (int)(cnt64[i] >> 32) : 0;
    int orig = v;
    int lane = t & 63, wv = t >> 6;
    #pragma unroll
    for (int o = 1; o < 64; o <<= 1) { int u = __shfl_up(v, o, 64); if (lane >= o) v += u; }
    if (lane == 63) ws_[wv] = v;
    __syncthreads();
    int add = bsum[b];
    for (int k = 0; k < wv; ++k) add += ws_[k];
    int incl = v + add;
    if (i < N) {
        rp[i + 1] = incl;
        cur[i] = incl - orig;                 // exclusive -> fill cursor
        if (i == 0) rp[0] = 0;
    }
}

// interleaved CSR: csr[p] = {src, float_bits(norm)} — one 8B store per edge
__global__ void fill_csr_k(const int* __restrict__ src, const int* __restrict__ dst,
                           const float* __restrict__ w, const float* __restrict__ dinv,
                           int* cur, uint2* __restrict__ csr, int E) {
    int e = blockIdx.x * blockDim.x + threadIdx.x;
    if (e < E) {
        int s = src[e], d = dst[e];
        int p = atomicAdd(&cur[d], 1);
        csr[p] = make_uint2((unsigned)s, __float_as_uint(dinv[s] * w[e] * dinv[d]));
    }
}

// ---------------- CSR gather, 2 edges/iter (bf16 in, f32 accum, bf16 out) ----------------
template <int EPI>
__global__ void agg_bf_k(const int* __restrict__ rp, const uint2* __restrict__ csr,
                         const unsigned short* __restrict__ X, int ldx2, int xo2,
                         const float* __restrict__ dinv, const float* __restrict__ bias,
                         unsigned short* __restrict__ Y, int ldy2, int yo2, int N) {
    int wid = (blockIdx.x * blockDim.x + threadIdx.x) >> 6;
    int lane = threadIdx.x & 63;
    if (wid >= N) return;
    const unsigned int* Xu = (const unsigned int*)X;
    int h = lane >> 5, c = lane & 31;

    float dv = dinv[wid]; dv *= dv;
    float w0 = h ? 0.f : dv;                   // self-loop only on even half
    uint2 sv = *(const uint2*)&Xu[(size_t)wid * ldx2 + xo2 + c * 2];
    float a0 = bf2f(sv.x & 0xffffu) * w0, a1 = bf2f(sv.x >> 16) * w0;
    float a2 = bf2f(sv.y & 0xffffu) * w0, a3 = bf2f(sv.y >> 16) * w0;

    int p = rp[wid], pe = rp[wid + 1];
    for (; p + 4 <= pe; p += 4) {              // 4 edges = 2 pairs
        uint2 eA = csr[p + h], eB = csr[p + 2 + h];
        float nA = __uint_as_float(eA.y), nB = __uint_as_float(eB.y);
        uint2 vA = *(const uint2*)&Xu[(size_t)eA.x * ldx2 + xo2 + c * 2];
        uint2 vB = *(const uint2*)&Xu[(size_t)eB.x * ldx2 + xo2 + c * 2];
        a0 = fmaf(bf2f(vA.x & 0xffffu), nA, a0); a1 = fmaf(bf2f(vA.x >> 16), nA, a1);
        a2 = fmaf(bf2f(vA.y & 0xffffu), nA, a2); a3 = fmaf(bf2f(vA.y >> 16), nA, a3);
        a0 = fmaf(bf2f(vB.x & 0xffffu), nB, a0); a1 = fmaf(bf2f(vB.x >> 16), nB, a1);
        a2 = fmaf(bf2f(vB.y & 0xffffu), nB, a2); a3 = fmaf(bf2f(vB.y >> 16), nB, a3);
    }
    if (p + 2 <= pe) {                         // one pair
        uint2 eA = csr[p + h];
        float nv = __uint_as_float(eA.y);
        uint2 v = *(const uint2*)&Xu[(size_t)eA.x * ldx2 + xo2 + c * 2];
        a0 = fmaf(bf2f(v.x & 0xffffu), nv, a0); a1 = fmaf(bf2f(v.x >> 16), nv, a1);
        a2 = fmaf(bf2f(v.y & 0xffffu), nv, a2); a3 = fmaf(bf2f(v.y >> 16), nv, a3);
        p += 2;
    }
    if (p < pe) {                              // odd tail: even half only
        uint2 eA = csr[p];
        float nv = h ? 0.f : __uint_as_float(eA.y);
        uint2 v = *(const uint2*)&Xu[(size_t)eA.x * ldx2 + xo2 + c * 2];
        a0 = fmaf(bf2f(v.x & 0xffffu), nv, a0); a1 = fmaf(bf2f(v.x >> 16), nv, a1);
        a2 = fmaf(bf2f(v.y & 0xffffu), nv, a2); a3 = fmaf(bf2f(v.y >> 16), nv, a3);
    }

    a0 += __shfl_xor(a0, 32);
    a1 += __shfl_xor(a1, 32);
    a2 += __shfl_xor(a2, 32);
    a3 += __shfl_xor(a3, 32);

    if (EPI == 1) {
        float4 bv = *(const float4*)&bias[c * 4];
        a0 = fmaxf(a0 + bv.x, 0.f); a1 = fmaxf(a1 + bv.y, 0.f);
        a2 = fmaxf(a2 + bv.z, 0.f); a3 = fmaxf(a3 + bv.w, 0.f);
    }
    if (h == 0) {
        uint2 o; o.x = pack2(a0, a1); o.y = pack2(a2, a3);
        *(uint2*)&((unsigned int*)Y)[(size_t)wid * ldy2 + yo2 + c * 2] = o;
    }
}

// ---------------- head: coalesced column sum ----------------

__global__ void colsum_bf_k(const unsigned short* __restrict__ Z, float* zsum, int N) {
    __shared__ float red[8][128];
    int t = threadIdx.x;
    int rg = t >> 5, c4 = (t & 31) * 4;
    int rpb = (N + gridDim.x - 1) / gridDim.x;
    int r0 = blockIdx.x * rpb, r1 = min(N, r0 + rpb);
    float s0 = 0.f, s1 = 0.f, s2 = 0.f, s3 = 0.f;
    for (int r = r0 + rg; r < r1; r += 8) {
        uint2 v = *(const uint2*)&Z[(size_t)r * 256 + c4];
        s0 += bf2f(v.x & 0xffffu); s1 += bf2f(v.x >> 16);
        s2 += bf2f(v.y & 0xffffu); s3 += bf2f(v.y >> 16);
    }
    red[rg][c4] = s0; red[rg][c4 + 1] = s1; red[rg][c4 + 2] = s2; red[rg][c4 + 3] = s3;
    __syncthreads();
    if (t < 128) {
        float s = 0.f;
        #pragma unroll
        for (int k = 0; k < 8; ++k) s += red[k][t];
        atomicAdd(&zsum[t], s);
    }
}

__global__ void head_k(const float* __restrict__ zsum, const float* __restrict__ Wh,
                       const float* __restrict__ bh, float* __restrict__ out, float invN) {
    __shared__ float red[128];
    int c = threadIdx.x;
    red[c] = zsum[c] * invN * Wh[c];
    __syncthreads();
    for (int s = 64; s > 0; s >>= 1) {
        if (c < s) red[c] += red[c + s];
        __syncthreads();
    }
    if (c == 0) out[0] = red[0] + bh[0];
}

// ---------------- bf16 MFMA GEMM, 128x128 tile, 512 threads, BK=64 ----------------

enum { EPI_G = 0, EPI_P = 1, EPI_ZR = 2, EPI_H = 3 };

__global__ __launch_bounds__(512)
void mm_bf16_k(const unsigned short* __restrict__ A0, const unsigned short* __restrict__ A1,
               int lda0, int lda1, int kb,
               const unsigned short* __restrict__ Bt, int K, int M, int ncb,
               const float* __restrict__ bias,
               const unsigned short* __restrict__ xb1, const unsigned short* __restrict__ xb2,
               void* __restrict__ out, void* __restrict__ out2, int epi)
{
    __shared__ unsigned short Als[2][8192];   // [buf][128 rows x 64 k]
    __shared__ unsigned short Bls[2][8192];

    // XCD-bijective swizzle, bcol fast
    int nwg = gridDim.x;
    int bid = blockIdx.x;
    int q = nwg >> 3, r = nwg & 7;
    int xcd = bid & 7;
    int wg = (xcd < r ? xcd * (q + 1) : r * (q + 1) + (xcd - r) * q) + (bid >> 3);
    int brow = wg / ncb, bcol = wg - brow * ncb;
    int row0 = brow * 128, col0 = bcol * 128;

    int t = threadIdx.x;
    int w = t >> 6, lane = t & 63;
    int wr = w >> 1, wc = w & 1;
    int m15 = lane & 15, g = lane >> 4;

    f32x4 acc[2][4];
    #pragma unroll
    for (int i = 0; i < 2; ++i)
        #pragma unroll
        for (int j = 0; j < 4; ++j)
            #pragma unroll
            for (int qq = 0; qq < 4; ++qq) acc[i][j][qq] = 0.f;

    auto stage = [&](int buf, int kt) {
        const unsigned short* Ap = A0; int lda = lda0; int ka = kt;
        if (kt >= kb) { Ap = A1; lda = lda1; ka = kt - kb; }
        #pragma unroll
        for (int i = 0; i < 2; ++i) {
            int idx = i * 512 + t;
            int row = idx >> 3, slot = idx & 7;
            int gk = (slot ^ (row & 7)) * 8;
            int gr = row0 + row; gr = gr < M ? gr : M - 1;
            GLOAD_LDS16(&Ap[(size_t)gr * lda + ka + gk], &Als[buf][(size_t)(i * 512 + w * 64) * 8]);
            GLOAD_LDS16(&Bt[(size_t)(col0 + row) * K + kt + gk], &Bls[buf][(size_t)(i * 512 + w * 64) * 8]);
        }
    };

    int NT = K >> 6;            // K in {128,256,512} -> 2,4,8
    stage(0, 0);
    int pb = 0;

    for (int ti = 0; ti < NT; ++ti) {
        if (ti + 1 < NT) {
            stage(pb ^ 1, (ti + 1) << 6);
            asm volatile("s_waitcnt vmcnt(4)" ::: "memory");
        } else {
            asm volatile("s_waitcnt vmcnt(0)" ::: "memory");
        }
        __builtin_amdgcn_s_barrier();
        __builtin_amdgcn_sched_barrier(0);

        short8 af[2][2], bfr[2][4];
        #pragma unroll
        for (int kk = 0; kk < 2; ++kk) {
            #pragma unroll
            for (int ms = 0; ms < 2; ++ms) {
                int rt = wr * 32 + ms * 16 + m15;
                af[kk][ms] = *(const short8*)&Als[pb][rt * 64 + (((kk * 4 + g) ^ (rt & 7)) << 3)];
            }
            #pragma unroll
            for (int ns = 0; ns < 4; ++ns) {
                int nt = wc * 64 + ns * 16 + m15;
                bfr[kk][ns] = *(const short8*)&Bls[pb][nt * 64 + (((kk * 4 + g) ^ (nt & 7)) << 3)];
            }
        }
        asm volatile("s_waitcnt lgkmcnt(0)" ::: "memory");
        __builtin_amdgcn_sched_barrier(0);
        __builtin_amdgcn_s_barrier();

        #pragma unroll
        for (int kk = 0; kk < 2; ++kk)
            #pragma unroll
            for (int ms = 0; ms < 2; ++ms)
                #pragma unroll
                for (int ns = 0; ns < 4; ++ns)
                    acc[ms][ns] = __builtin_amdgcn_mfma_f32_16x16x32_bf16(bfr[kk][ns], af[kk][ms], acc[ms][ns], 0, 0, 0);
        pb ^= 1;
    }

    // epilogue: row = row0 + wr*32 + ms*16 + m15 ; cols = col0 + wc*64 + ns*16 + g*4 + (0..3)
    #pragma unroll
    for (int ms = 0; ms < 2; ++ms) {
        int row = row0 + wr * 32 + ms * 16 + m15;
        bool rok = row < M;
        #pragma unroll
        for (int ns = 0; ns < 4; ++ns) {
            int col = col0 + wc * 64 + ns * 16 + g * 4;
            f32x4 a = acc[ms][ns];
            if (epi == EPI_G) {
                float4 bv = *(const float4*)&bias[col];
                uint2 p4 = *(const uint2*)&xb1[(size_t)row * 256 + col];
                uint2 o;
                o.x = pack2(fmaxf(a[0] + bv.x, 0.f) + bf2f(p4.x & 0xffffu),
                            fmaxf(a[1] + bv.y, 0.f) + bf2f(p4.x >> 16));
                o.y = pack2(fmaxf(a[2] + bv.z, 0.f) + bf2f(p4.y & 0xffffu),
                            fmaxf(a[3] + bv.w, 0.f) + bf2f(p4.y >> 16));
                if (rok) *(uint2*)&((unsigned short*)out)[(size_t)row * 256 + col] = o;
            } else if (epi == EPI_P) {
                uint2 o;
                o.x = pack2(a[0], a[1]);
                o.y = pack2(a[2], a[3]);
                if (rok) *(uint2*)&((unsigned short*)out)[(size_t)row * 128 + col] = o;
            } else if (epi == EPI_ZR) {
                float4 bv = *(const float4*)&bias[col];
                float s0 = 1.f / (1.f + __expf(-(a[0] + bv.x)));
                float s1 = 1.f / (1.f + __expf(-(a[1] + bv.y)));
                float s2 = 1.f / (1.f + __expf(-(a[2] + bv.z)));
                float s3 = 1.f / (1.f + __expf(-(a[3] + bv.w)));
                if (col < 256) {
                    uint2 o; o.x = pack2(s0, s1); o.y = pack2(s2, s3);
                    if (rok) *(uint2*)&((unsigned short*)out)[(size_t)row * 256 + col] = o;
                } else {
                    int c2 = col - 256;
                    uint2 p4 = *(const uint2*)&xb1[(size_t)row * 256 + c2];
                    uint2 o;
                    o.x = pack2(bf2f(p4.x & 0xffffu) * s0, bf2f(p4.x >> 16) * s1);
                    o.y = pack2(bf2f(p4.y & 0xffffu) * s2, bf2f(p4.y >> 16) * s3);
                    if (rok) *(uint2*)&((unsigned short*)out2)[(size_t)row * 256 + c2] = o;
                }
            } else {  // EPI_H
                float4 bv = *(const float4*)&bias[col];
                uint2 z4 = *(const uint2*)&xb2[(size_t)row * 256 + col];
                uint2 p4 = *(const uint2*)&xb1[(size_t)row * 256 + col];
                float4 o;
                {
                    float s = a[0] + bv.x, e = __expf(2.f * s);
                    float ht = 1.f - 2.f / (e + 1.f);
                    float Zt = bf2f(z4.x & 0xffffu), ph = bf2f(p4.x & 0xffffu);
                    o.x = Zt * ph + (1.f - Zt) * ht;
                }
                {
                    float s = a[1] + bv.y, e = __expf(2.f * s);
                    float ht = 1.f - 2.f / (e + 1.f);
                    float Zt = bf2f(z4.x >> 16), ph = bf2f(p4.x >> 16);
                    o.y = Zt * ph + (1.f - Zt) * ht;
                }
                {
                    float s = a[2] + bv.z, e = __expf(2.f * s);
                    float ht = 1.f - 2.f / (e + 1.f);
                    float Zt = bf2f(z4.y & 0xffffu), ph = bf2f(p4.y & 0xffffu);
                    o.z = Zt * ph + (1.f - Zt) * ht;
                }
                {
                    float s = a[3] + bv.w, e = __expf(2.f * s);
                    float ht = 1.f - 2.f / (e + 1.f);
                    float Zt = bf2f(z4.y >> 16), ph = bf2f(p4.y >> 16);
                    o.w = Zt * ph + (1.f - Zt) * ht;
                }
                if (rok) *(float4*)&((float*)out)[(size_t)row * 256 + col] = o;
            }
        }
    }
}

// ---------------- launch ----------------

extern "C" void kernel_launch(void* const* d_in, const int* in_sizes, int n_in,
                              void* d_out, int out_size, void* d_ws, size_t ws_size,
                              hipStream_t stream) {
    const float* x      = (const float*)d_in[0];
    const int*   ei     = (const int*)d_in[1];
    const float* ew     = (const float*)d_in[2];
    const float* prev_h = (const float*)d_in[3];
    const float* W1  = (const float*)d_in[4];  const float* b1  = (const float*)d_in[5];
    const float* W2  = (const float*)d_in[6];  const float* b2  = (const float*)d_in[7];
    const float* Wxz = (const float*)d_in[8];  const float* bxz = (const float*)d_in[9];
    const float* Whz = (const float*)d_in[10]; const float* bhz = (const float*)d_in[11];
    const float* Wxr = (const float*)d_in[12]; const float* bxr = (const float*)d_in[13];
    const float* Whr = (const float*)d_in[14]; const float* bhr = (const float*)d_in[15];
    const float* Wxh = (const float*)d_in[16]; const float* bxh = (const float*)d_in[17];
    const float* Whh = (const float*)d_in[18]; const float* bhh = (const float*)d_in[19];
    const float* Whead = (const float*)d_in[20]; const float* bhead = (const float*)d_in[21];

    const int N = in_sizes[0] / 128;
    const int E = in_sizes[2];
    const int* esrc = ei;
    const int* edst = ei + E;

    float* ws = (float*)d_ws;
    size_t o = 0;
    float* dinv     = ws + o; o += (size_t)N;
    unsigned long long* cnt64 = (unsigned long long*)(ws + o); o += (size_t)N * 2;
    int*   cur      = (int*)(ws + o); o += (size_t)N;
    int*   rowp     = (int*)(ws + o); o += (size_t)N + 4;
    int*   bsum     = (int*)(ws + o); o += 256;
    uint2* csr      = (uint2*)(ws + o); o += (size_t)E * 2;
    unsigned short* zx   = (unsigned short*)(ws + o); o += (size_t)N * 128;  // [N,256]: z | x
    unsigned short* phb  = (unsigned short*)(ws + o); o += (size_t)N * 128;  // prev_h bf16
    unsigned short* buf1 = (unsigned short*)(ws + o); o += (size_t)N * 128;  // t -> gw2 -> q
    unsigned short* Zbf  = (unsigned short*)(ws + o); o += (size_t)N * 128;  // g_bf -> Z bf16
    unsigned short* Bt1  = (unsigned short*)(ws + o); o += 16384;
    unsigned short* Bt2  = (unsigned short*)(ws + o); o += 16384;
    unsigned short* BtZR = (unsigned short*)(ws + o); o += 131072;
    unsigned short* BtH  = (unsigned short*)(ws + o); o += 65536;
    float* bZR      = ws + o; o += 512;
    float* bH       = ws + o; o += 256;
    float* zsum     = ws + o; o += 128;

    unsigned short* g_bf = Zbf;
    float* hout = (float*)d_out + 1;

    const int TPB = 256;
    int gE = (E + TPB - 1) / TPB;
    int gAgg = (N * 64 + TPB - 1) / TPB;
    int nb = (N + 127) / 128;
    int nsb = (N + 255) / 256;          // scan blocks (must be <= 256)

    // prep: cnt64 zero + x,prev_h -> bf16 + zsum=0
    {
        long long tot = (long long)N * 98 + 128;
        prep_k<<<(int)((tot + TPB - 1) / TPB), TPB, 0, stream>>>(x, prev_h, cnt64, zx, phb, zsum, N);
    }
    // weights + biases
    {
        const int cvtw_total = 2 * 32768 + 6 * 65536 + 768;
        cvtwb_k<<<(cvtw_total + TPB - 1) / TPB, TPB, 0, stream>>>(
            W1, W2, Wxz, Whz, Wxr, Whr, Wxh, Whh,
            bxz, bhz, bxr, bhr, bxh, bhh, Bt1, Bt2, BtZR, BtH, bZR, bH);
    }

    // degree + CSR
    deg_cnt_k<<<gE, TPB, 0, stream>>>(edst, ew, cnt64, E);
    scan1_k<<<nsb, 256, 0, stream>>>(cnt64, bsum, dinv, N);
    scan2_k<<<1, 256, 0, stream>>>(bsum, nsb);
    scan3_k<<<nsb, 256, 0, stream>>>(cnt64, bsum, rowp, cur, N);
    fill_csr_k<<<gE, TPB, 0, stream>>>(esrc, edst, ew, dinv, cur, csr, E);

    // t = agg(x)
    agg_bf_k<0><<<gAgg, TPB, 0, stream>>>(rowp, csr, zx, 128, 64, dinv,
                                          nullptr, buf1, 64, 0, N);

    // g = relu(t@W1 + b1) + prev_h
    mm_bf16_k<<<nb * 2, 512, 0, stream>>>(buf1, buf1, 128, 128, 128, Bt1, 128, N, 2,
                                          b1, phb, nullptr, g_bf, nullptr, EPI_G);
    // gw2 = g@W2
    mm_bf16_k<<<nb, 512, 0, stream>>>(g_bf, g_bf, 256, 256, 256, Bt2, 256, N, 1,
                                      nullptr, nullptr, nullptr, buf1, nullptr, EPI_P);
    // z = relu(agg(gw2) + b2)
    agg_bf_k<1><<<gAgg, TPB, 0, stream>>>(rowp, csr, buf1, 64, 0, dinv,
                                          b2, zx, 128, 0, N);

    // head
    colsum_bf_k<<<256, 256, 0, stream>>>(zx, zsum, N);
    head_k<<<1, 128, 0, stream>>>(zsum, Whead, bhead, (float*)d_out, 1.0f / (float)N);

    // Z|R fused GEMM
    mm_bf16_k<<<nb * 4, 512, 0, stream>>>(zx, phb, 256, 256, 256, BtZR, 512, N, 4,
                                          bZR, phb, nullptr, Zbf, buf1, EPI_ZR);
    // h GEMM
    mm_bf16_k<<<nb * 2, 512, 0, stream>>>(zx, buf1, 256, 256, 256, BtH, 512, N, 2,
                                          bH, phb, Zbf, hout, nullptr, EPI_H);
}

// Round 14
// 368.227 us; speedup vs baseline: 1.5493x; 1.0056x over previous
//
#include <hip/hip_runtime.h>
#include <math.h>

typedef __attribute__((ext_vector_type(8))) short short8;   // 8 bf16 = 4 VGPR
typedef __attribute__((ext_vector_type(4))) float f32x4;

__device__ inline unsigned short f2bf(float f) {
    unsigned int u = __float_as_uint(f);
    u += 0x7fffu + ((u >> 16) & 1u);          // RNE
    return (unsigned short)(u >> 16);
}
__device__ inline float bf2f(unsigned int h) { return __uint_as_float(h << 16); }
__device__ inline unsigned pack2(float a, float b) {
    return (unsigned)f2bf(a) | ((unsigned)f2bf(b) << 16);
}

#define GLOAD_LDS16(gp, lp)                                                              \
    __builtin_amdgcn_global_load_lds(                                                    \
        (const __attribute__((address_space(1))) unsigned int*)(const void*)(gp),        \
        (__attribute__((address_space(3))) unsigned int*)(void*)(lp), 16, 0, 0)

// ---------------- fused prep: cnt64 zero + x->bf16 + prev_h->bf16 + zsum=0 ----------------

__global__ void prep_k(const float* __restrict__ x, const float* __restrict__ ph,
                       unsigned long long* __restrict__ cnt64,
                       unsigned short* __restrict__ zx, unsigned short* __restrict__ phb,
                       float* __restrict__ zsum, int N) {
    int t = blockIdx.x * blockDim.x + threadIdx.x;
    if (t < 2 * N) { ((int*)cnt64)[t] = 0; return; }
    t -= 2 * N;
    if (t < N * 32) {           // cvt_x -> zx cols 128..255
        int r = t >> 5, c4 = (t & 31) * 4;
        float4 v = *(const float4*)&x[(size_t)r * 128 + c4];
        uint2 o; o.x = pack2(v.x, v.y); o.y = pack2(v.z, v.w);
        *(uint2*)&zx[(size_t)r * 256 + 128 + c4] = o;
        return;
    }
    t -= N * 32;
    if (t < N * 64) {           // cvt_ph
        int r = t >> 6, c4 = (t & 63) * 4;
        float4 v = *(const float4*)&ph[(size_t)r * 256 + c4];
        uint2 o; o.x = pack2(v.x, v.y); o.y = pack2(v.z, v.w);
        *(uint2*)&phb[(size_t)r * 256 + c4] = o;
        return;
    }
    t -= N * 64;
    if (t < 128) zsum[t] = 0.f;
}

// ---------------- weights -> bf16 transposed + fused biases ----------------

__global__ void cvtwb_k(const float* W1, const float* W2,
                        const float* Wxz, const float* Whz, const float* Wxr, const float* Whr,
                        const float* Wxh, const float* Whh,
                        const float* bxz, const float* bhz, const float* bxr, const float* bhr,
                        const float* bxh, const float* bhh,
                        unsigned short* Bt1, unsigned short* Bt2,
                        unsigned short* BtZR, unsigned short* BtH,
                        float* bZR, float* bH) {
    int t = blockIdx.x * blockDim.x + threadIdx.x;
    if (t < 32768) { int k = t >> 8, n = t & 255; Bt1[(size_t)n * 128 + k] = f2bf(W1[t]); return; }
    t -= 32768;
    if (t < 32768) { int k = t >> 7, n = t & 127; Bt2[(size_t)n * 256 + k] = f2bf(W2[t]); return; }
    t -= 32768;
    if (t < 65536) { int k = t >> 8, n = t & 255; BtZR[(size_t)n * 512 + k] = f2bf(Wxz[t]); return; }
    t -= 65536;
    if (t < 65536) { int k = t >> 8, n = t & 255; BtZR[(size_t)n * 512 + 256 + k] = f2bf(Whz[t]); return; }
    t -= 65536;
    if (t < 65536) { int k = t >> 8, n = t & 255; BtZR[(size_t)(256 + n) * 512 + k] = f2bf(Wxr[t]); return; }
    t -= 65536;
    if (t < 65536) { int k = t >> 8, n = t & 255; BtZR[(size_t)(256 + n) * 512 + 256 + k] = f2bf(Whr[t]); return; }
    t -= 65536;
    if (t < 65536) { int k = t >> 8, n = t & 255; BtH[(size_t)n * 512 + k] = f2bf(Wxh[t]); return; }
    t -= 65536;
    if (t < 65536) { int k = t >> 8, n = t & 255; BtH[(size_t)n * 512 + 256 + k] = f2bf(Whh[t]); return; }
    t -= 65536;
    if (t < 256)       bZR[t] = bxz[t] + bhz[t];
    else if (t < 512)  bZR[t] = bxr[t - 256] + bhr[t - 256];
    else if (t < 768)  bH[t - 512] = bxh[t - 512] + bhh[t - 512];
}

// ---------------- degree+count: ONE u64 atomic per edge ----------------

__global__ void deg_cnt_k(const int* __restrict__ dst, const float* __restrict__ w,
                          unsigned long long* cnt64, int E) {
    int e = blockIdx.x * blockDim.x + threadIdx.x;
    if (e < E) {
        unsigned wfix = __float2uint_rn(w[e] * 16777216.0f);
        atomicAdd(&cnt64[dst[e]], (1ULL << 32) | (unsigned long long)wfix);
    }
}

// scan1: decode cnt64 -> cnt (hi) + dinv (1 + lo/2^24); block sums for scan
__global__ void scan1_k(const unsigned long long* __restrict__ cnt64, int* __restrict__ bsum,
                        float* __restrict__ dinv, int N) {
    __shared__ int ws_[4];
    int b = blockIdx.x, t = threadIdx.x;
    int i = b * 256 + t;
    unsigned long long v64 = (i < N) ? cnt64[i] : 0ULL;
    if (i < N) {
        float deg = 1.0f + (float)(unsigned)(v64 & 0xffffffffu) * (1.0f / 16777216.0f);
        dinv[i] = rsqrtf(deg);                 // deg >= 1 always
    }
    int v = (int)(v64 >> 32);
    int lane = t & 63, wv = t >> 6;
    #pragma unroll
    for (int o = 1; o < 64; o <<= 1) { int u = __shfl_up(v, o, 64); if (lane >= o) v += u; }
    if (lane == 63) ws_[wv] = v;
    __syncthreads();
    if (t == 0) bsum[b] = ws_[0] + ws_[1] + ws_[2] + ws_[3];
}

__global__ void scan2_k(int* __restrict__ bsum, int nb) {
    __shared__ int ws_[4];
    int t = threadIdx.x;
    int v = (t < nb) ? bsum[t] : 0;
    int orig = v;
    int lane = t & 63, wv = t >> 6;
    #pragma unroll
    for (int o = 1; o < 64; o <<= 1) { int u = __shfl_up(v, o, 64); if (lane >= o) v += u; }
    if (lane == 63) ws_[wv] = v;
    __syncthreads();
    int add = 0;
    for (int k = 0; k < wv; ++k) add += ws_[k];
    if (t < nb) bsum[t] = v + add - orig;     // exclusive block offset
}

__global__ void scan3_k(const unsigned long long* __restrict__ cnt64, const int* __restrict__ bsum,
                        int* __restrict__ rp, int* __restrict__ cur, int N) {
    __shared__ int ws_[4];
    int b = blockIdx.x, t = threadIdx.x;
    int i = b * 256 + t;
    int v = (i < N) ? (int)(cnt64[i] >> 32) : 0;
    int orig = v;
    int lane = t & 63, wv = t >> 6;
    #pragma unroll
    for (int o = 1; o < 64; o <<= 1) { int u = __shfl_up(v, o, 64); if (lane >= o) v += u; }
    if (lane == 63) ws_[wv] = v;
    __syncthreads();
    int add = bsum[b];
    for (int k = 0; k < wv; ++k) add += ws_[k];
    int incl = v + add;
    if (i < N) {
        rp[i + 1] = incl;
        cur[i] = incl - orig;                 // exclusive -> fill cursor
        if (i == 0) rp[0] = 0;
    }
}

// interleaved CSR: csr[p] = {src, float_bits(norm)} — one 8B store per edge
__global__ void fill_csr_k(const int* __restrict__ src, const int* __restrict__ dst,
                           const float* __restrict__ w, const float* __restrict__ dinv,
                           int* cur, uint2* __restrict__ csr, int E) {
    int e = blockIdx.x * blockDim.x + threadIdx.x;
    if (e < E) {
        int s = src[e], d = dst[e];
        int p = atomicAdd(&cur[d], 1);
        csr[p] = make_uint2((unsigned)s, __float_as_uint(dinv[s] * w[e] * dinv[d]));
    }
}

// ---------------- CSR gather, 2 edges/iter (bf16 in, f32 accum, bf16 out) ----------------
template <int EPI>
__global__ void agg_bf_k(const int* __restrict__ rp, const uint2* __restrict__ csr,
                         const unsigned short* __restrict__ X, int ldx2, int xo2,
                         const float* __restrict__ dinv, const float* __restrict__ bias,
                         unsigned short* __restrict__ Y, int ldy2, int yo2, int N) {
    int wid = (blockIdx.x * blockDim.x + threadIdx.x) >> 6;
    int lane = threadIdx.x & 63;
    if (wid >= N) return;
    const unsigned int* Xu = (const unsigned int*)X;
    int h = lane >> 5, c = lane & 31;

    float dv = dinv[wid]; dv *= dv;
    float w0 = h ? 0.f : dv;                   // self-loop only on even half
    uint2 sv = *(const uint2*)&Xu[(size_t)wid * ldx2 + xo2 + c * 2];
    float a0 = bf2f(sv.x & 0xffffu) * w0, a1 = bf2f(sv.x >> 16) * w0;
    float a2 = bf2f(sv.y & 0xffffu) * w0, a3 = bf2f(sv.y >> 16) * w0;

    int p = rp[wid], pe = rp[wid + 1];
    for (; p + 4 <= pe; p += 4) {              // 4 edges = 2 pairs
        uint2 eA = csr[p + h], eB = csr[p + 2 + h];
        float nA = __uint_as_float(eA.y), nB = __uint_as_float(eB.y);
        uint2 vA = *(const uint2*)&Xu[(size_t)eA.x * ldx2 + xo2 + c * 2];
        uint2 vB = *(const uint2*)&Xu[(size_t)eB.x * ldx2 + xo2 + c * 2];
        a0 = fmaf(bf2f(vA.x & 0xffffu), nA, a0); a1 = fmaf(bf2f(vA.x >> 16), nA, a1);
        a2 = fmaf(bf2f(vA.y & 0xffffu), nA, a2); a3 = fmaf(bf2f(vA.y >> 16), nA, a3);
        a0 = fmaf(bf2f(vB.x & 0xffffu), nB, a0); a1 = fmaf(bf2f(vB.x >> 16), nB, a1);
        a2 = fmaf(bf2f(vB.y & 0xffffu), nB, a2); a3 = fmaf(bf2f(vB.y >> 16), nB, a3);
    }
    if (p + 2 <= pe) {                         // one pair
        uint2 eA = csr[p + h];
        float nv = __uint_as_float(eA.y);
        uint2 v = *(const uint2*)&Xu[(size_t)eA.x * ldx2 + xo2 + c * 2];
        a0 = fmaf(bf2f(v.x & 0xffffu), nv, a0); a1 = fmaf(bf2f(v.x >> 16), nv, a1);
        a2 = fmaf(bf2f(v.y & 0xffffu), nv, a2); a3 = fmaf(bf2f(v.y >> 16), nv, a3);
        p += 2;
    }
    if (p < pe) {                              // odd tail: even half only
        uint2 eA = csr[p];
        float nv = h ? 0.f : __uint_as_float(eA.y);
        uint2 v = *(const uint2*)&Xu[(size_t)eA.x * ldx2 + xo2 + c * 2];
        a0 = fmaf(bf2f(v.x & 0xffffu), nv, a0); a1 = fmaf(bf2f(v.x >> 16), nv, a1);
        a2 = fmaf(bf2f(v.y & 0xffffu), nv, a2); a3 = fmaf(bf2f(v.y >> 16), nv, a3);
    }

    a0 += __shfl_xor(a0, 32);
    a1 += __shfl_xor(a1, 32);
    a2 += __shfl_xor(a2, 32);
    a3 += __shfl_xor(a3, 32);

    if (EPI == 1) {
        float4 bv = *(const float4*)&bias[c * 4];
        a0 = fmaxf(a0 + bv.x, 0.f); a1 = fmaxf(a1 + bv.y, 0.f);
        a2 = fmaxf(a2 + bv.z, 0.f); a3 = fmaxf(a3 + bv.w, 0.f);
    }
    if (h == 0) {
        uint2 o; o.x = pack2(a0, a1); o.y = pack2(a2, a3);
        *(uint2*)&((unsigned int*)Y)[(size_t)wid * ldy2 + yo2 + c * 2] = o;
    }
}

// ---------------- head: coalesced column sum ----------------

__global__ void colsum_bf_k(const unsigned short* __restrict__ Z, float* zsum, int N) {
    __shared__ float red[8][128];
    int t = threadIdx.x;
    int rg = t >> 5, c4 = (t & 31) * 4;
    int rpb = (N + gridDim.x - 1) / gridDim.x;
    int r0 = blockIdx.x * rpb, r1 = min(N, r0 + rpb);
    float s0 = 0.f, s1 = 0.f, s2 = 0.f, s3 = 0.f;
    for (int r = r0 + rg; r < r1; r += 8) {
        uint2 v = *(const uint2*)&Z[(size_t)r * 256 + c4];
        s0 += bf2f(v.x & 0xffffu); s1 += bf2f(v.x >> 16);
        s2 += bf2f(v.y & 0xffffu); s3 += bf2f(v.y >> 16);
    }
    red[rg][c4] = s0; red[rg][c4 + 1] = s1; red[rg][c4 + 2] = s2; red[rg][c4 + 3] = s3;
    __syncthreads();
    if (t < 128) {
        float s = 0.f;
        #pragma unroll
        for (int k = 0; k < 8; ++k) s += red[k][t];
        atomicAdd(&zsum[t], s);
    }
}

__global__ void head_k(const float* __restrict__ zsum, const float* __restrict__ Wh,
                       const float* __restrict__ bh, float* __restrict__ out, float invN) {
    __shared__ float red[128];
    int c = threadIdx.x;
    red[c] = zsum[c] * invN * Wh[c];
    __syncthreads();
    for (int s = 64; s > 0; s >>= 1) {
        if (c < s) red[c] += red[c + s];
        __syncthreads();
    }
    if (c == 0) out[0] = red[0] + bh[0];
}

// ---------------- bf16 MFMA GEMM, 128x128 tile, 512 threads, BK=64 ----------------
// SINGLE-BARRIER pipeline: per K-step, __syncthreads() (drains own vmcnt) then
// issue next-tile stage AFTER the barrier (safe: all waves' reads of that buffer
// completed before they reached this barrier, enforced by MFMA data deps).
// Compiler schedules ds_read<->MFMA overlap with fine-grained lgkmcnt.

enum { EPI_G = 0, EPI_P = 1, EPI_ZR = 2, EPI_H = 3 };

__global__ __launch_bounds__(512)
void mm_bf16_k(const unsigned short* __restrict__ A0, const unsigned short* __restrict__ A1,
               int lda0, int lda1, int kb,
               const unsigned short* __restrict__ Bt, int K, int M, int ncb,
               const float* __restrict__ bias,
               const unsigned short* __restrict__ xb1, const unsigned short* __restrict__ xb2,
               void* __restrict__ out, void* __restrict__ out2, int epi)
{
    __shared__ unsigned short Als[2][8192];   // [buf][128 rows x 64 k]
    __shared__ unsigned short Bls[2][8192];

    // XCD-bijective swizzle, bcol fast
    int nwg = gridDim.x;
    int bid = blockIdx.x;
    int q = nwg >> 3, r = nwg & 7;
    int xcd = bid & 7;
    int wg = (xcd < r ? xcd * (q + 1) : r * (q + 1) + (xcd - r) * q) + (bid >> 3);
    int brow = wg / ncb, bcol = wg - brow * ncb;
    int row0 = brow * 128, col0 = bcol * 128;

    int t = threadIdx.x;
    int w = t >> 6, lane = t & 63;
    int wr = w >> 1, wc = w & 1;
    int m15 = lane & 15, g = lane >> 4;

    f32x4 acc[2][4];
    #pragma unroll
    for (int i = 0; i < 2; ++i)
        #pragma unroll
        for (int j = 0; j < 4; ++j)
            #pragma unroll
            for (int qq = 0; qq < 4; ++qq) acc[i][j][qq] = 0.f;

    auto stage = [&](int buf, int kt) {
        const unsigned short* Ap = A0; int lda = lda0; int ka = kt;
        if (kt >= kb) { Ap = A1; lda = lda1; ka = kt - kb; }
        #pragma unroll
        for (int i = 0; i < 2; ++i) {
            int idx = i * 512 + t;
            int row = idx >> 3, slot = idx & 7;
            int gk = (slot ^ (row & 7)) * 8;
            int gr = row0 + row; gr = gr < M ? gr : M - 1;
            GLOAD_LDS16(&Ap[(size_t)gr * lda + ka + gk], &Als[buf][(size_t)(i * 512 + w * 64) * 8]);
            GLOAD_LDS16(&Bt[(size_t)(col0 + row) * K + kt + gk], &Bls[buf][(size_t)(i * 512 + w * 64) * 8]);
        }
    };

    int NT = K >> 6;            // K in {128,256,512} -> 2,4,8
    stage(0, 0);
    int pb = 0;

    for (int ti = 0; ti < NT; ++ti) {
        __syncthreads();                        // drains own vmcnt(0): tile ti staged; syncs waves
        if (ti + 1 < NT) stage(pb ^ 1, (ti + 1) << 6);   // safe after barrier

        short8 af[2][2], bfr[2][4];
        #pragma unroll
        for (int kk = 0; kk < 2; ++kk) {
            #pragma unroll
            for (int ms = 0; ms < 2; ++ms) {
                int rt = wr * 32 + ms * 16 + m15;
                af[kk][ms] = *(const short8*)&Als[pb][rt * 64 + (((kk * 4 + g) ^ (rt & 7)) << 3)];
            }
            #pragma unroll
            for (int ns = 0; ns < 4; ++ns) {
                int nt = wc * 64 + ns * 16 + m15;
                bfr[kk][ns] = *(const short8*)&Bls[pb][nt * 64 + (((kk * 4 + g) ^ (nt & 7)) << 3)];
            }
        }
        #pragma unroll
        for (int kk = 0; kk < 2; ++kk)
            #pragma unroll
            for (int ms = 0; ms < 2; ++ms)
                #pragma unroll
                for (int ns = 0; ns < 4; ++ns)
                    acc[ms][ns] = __builtin_amdgcn_mfma_f32_16x16x32_bf16(bfr[kk][ns], af[kk][ms], acc[ms][ns], 0, 0, 0);
        pb ^= 1;
    }

    // epilogue: row = row0 + wr*32 + ms*16 + m15 ; cols = col0 + wc*64 + ns*16 + g*4 + (0..3)
    #pragma unroll
    for (int ms = 0; ms < 2; ++ms) {
        int row = row0 + wr * 32 + ms * 16 + m15;
        bool rok = row < M;
        #pragma unroll
        for (int ns = 0; ns < 4; ++ns) {
            int col = col0 + wc * 64 + ns * 16 + g * 4;
            f32x4 a = acc[ms][ns];
            if (epi == EPI_G) {
                float4 bv = *(const float4*)&bias[col];
                uint2 p4 = *(const uint2*)&xb1[(size_t)row * 256 + col];
                uint2 o;
                o.x = pack2(fmaxf(a[0] + bv.x, 0.f) + bf2f(p4.x & 0xffffu),
                            fmaxf(a[1] + bv.y, 0.f) + bf2f(p4.x >> 16));
                o.y = pack2(fmaxf(a[2] + bv.z, 0.f) + bf2f(p4.y & 0xffffu),
                            fmaxf(a[3] + bv.w, 0.f) + bf2f(p4.y >> 16));
                if (rok) *(uint2*)&((unsigned short*)out)[(size_t)row * 256 + col] = o;
            } else if (epi == EPI_P) {
                uint2 o;
                o.x = pack2(a[0], a[1]);
                o.y = pack2(a[2], a[3]);
                if (rok) *(uint2*)&((unsigned short*)out)[(size_t)row * 128 + col] = o;
            } else if (epi == EPI_ZR) {
                float4 bv = *(const float4*)&bias[col];
                float s0 = 1.f / (1.f + __expf(-(a[0] + bv.x)));
                float s1 = 1.f / (1.f + __expf(-(a[1] + bv.y)));
                float s2 = 1.f / (1.f + __expf(-(a[2] + bv.z)));
                float s3 = 1.f / (1.f + __expf(-(a[3] + bv.w)));
                if (col < 256) {
                    uint2 o; o.x = pack2(s0, s1); o.y = pack2(s2, s3);
                    if (rok) *(uint2*)&((unsigned short*)out)[(size_t)row * 256 + col] = o;
                } else {
                    int c2 = col - 256;
                    uint2 p4 = *(const uint2*)&xb1[(size_t)row * 256 + c2];
                    uint2 o;
                    o.x = pack2(bf2f(p4.x & 0xffffu) * s0, bf2f(p4.x >> 16) * s1);
                    o.y = pack2(bf2f(p4.y & 0xffffu) * s2, bf2f(p4.y >> 16) * s3);
                    if (rok) *(uint2*)&((unsigned short*)out2)[(size_t)row * 256 + c2] = o;
                }
            } else {  // EPI_H
                float4 bv = *(const float4*)&bias[col];
                uint2 z4 = *(const uint2*)&xb2[(size_t)row * 256 + col];
                uint2 p4 = *(const uint2*)&xb1[(size_t)row * 256 + col];
                float4 o;
                {
                    float s = a[0] + bv.x, e = __expf(2.f * s);
                    float ht = 1.f - 2.f / (e + 1.f);
                    float Zt = bf2f(z4.x & 0xffffu), ph = bf2f(p4.x & 0xffffu);
                    o.x = Zt * ph + (1.f - Zt) * ht;
                }
                {
                    float s = a[1] + bv.y, e = __expf(2.f * s);
                    float ht = 1.f - 2.f / (e + 1.f);
                    float Zt = bf2f(z4.x >> 16), ph = bf2f(p4.x >> 16);
                    o.y = Zt * ph + (1.f - Zt) * ht;
                }
                {
                    float s = a[2] + bv.z, e = __expf(2.f * s);
                    float ht = 1.f - 2.f / (e + 1.f);
                    float Zt = bf2f(z4.y & 0xffffu), ph = bf2f(p4.y & 0xffffu);
                    o.z = Zt * ph + (1.f - Zt) * ht;
                }
                {
                    float s = a[3] + bv.w, e = __expf(2.f * s);
                    float ht = 1.f - 2.f / (e + 1.f);
                    float Zt = bf2f(z4.y >> 16), ph = bf2f(p4.y >> 16);
                    o.w = Zt * ph + (1.f - Zt) * ht;
                }
                if (rok) *(float4*)&((float*)out)[(size_t)row * 256 + col] = o;
            }
        }
    }
}

// ---------------- launch ----------------

extern "C" void kernel_launch(void* const* d_in, const int* in_sizes, int n_in,
                              void* d_out, int out_size, void* d_ws, size_t ws_size,
                              hipStream_t stream) {
    const float* x      = (const float*)d_in[0];
    const int*   ei     = (const int*)d_in[1];
    const float* ew     = (const float*)d_in[2];
    const float* prev_h = (const float*)d_in[3];
    const float* W1  = (const float*)d_in[4];  const float* b1  = (const float*)d_in[5];
    const float* W2  = (const float*)d_in[6];  const float* b2  = (const float*)d_in[7];
    const float* Wxz = (const float*)d_in[8];  const float* bxz = (const float*)d_in[9];
    const float* Whz = (const float*)d_in[10]; const float* bhz = (const float*)d_in[11];
    const float* Wxr = (const float*)d_in[12]; const float* bxr = (const float*)d_in[13];
    const float* Whr = (const float*)d_in[14]; const float* bhr = (const float*)d_in[15];
    const float* Wxh = (const float*)d_in[16]; const float* bxh = (const float*)d_in[17];
    const float* Whh = (const float*)d_in[18]; const float* bhh = (const float*)d_in[19];
    const float* Whead = (const float*)d_in[20]; const float* bhead = (const float*)d_in[21];

    const int N = in_sizes[0] / 128;
    const int E = in_sizes[2];
    const int* esrc = ei;
    const int* edst = ei + E;

    float* ws = (float*)d_ws;
    size_t o = 0;
    float* dinv     = ws + o; o += (size_t)N;
    unsigned long long* cnt64 = (unsigned long long*)(ws + o); o += (size_t)N * 2;
    int*   cur      = (int*)(ws + o); o += (size_t)N;
    int*   rowp     = (int*)(ws + o); o += (size_t)N + 4;
    int*   bsum     = (int*)(ws + o); o += 256;
    uint2* csr      = (uint2*)(ws + o); o += (size_t)E * 2;
    unsigned short* zx   = (unsigned short*)(ws + o); o += (size_t)N * 128;  // [N,256]: z | x
    unsigned short* phb  = (unsigned short*)(ws + o); o += (size_t)N * 128;  // prev_h bf16
    unsigned short* buf1 = (unsigned short*)(ws + o); o += (size_t)N * 128;  // t -> gw2 -> q
    unsigned short* Zbf  = (unsigned short*)(ws + o); o += (size_t)N * 128;  // g_bf -> Z bf16
    unsigned short* Bt1  = (unsigned short*)(ws + o); o += 16384;
    unsigned short* Bt2  = (unsigned short*)(ws + o); o += 16384;
    unsigned short* BtZR = (unsigned short*)(ws + o); o += 131072;
    unsigned short* BtH  = (unsigned short*)(ws + o); o += 65536;
    float* bZR      = ws + o; o += 512;
    float* bH       = ws + o; o += 256;
    float* zsum     = ws + o; o += 128;

    unsigned short* g_bf = Zbf;
    float* hout = (float*)d_out + 1;

    const int TPB = 256;
    int gE = (E + TPB - 1) / TPB;
    int gAgg = (N * 64 + TPB - 1) / TPB;
    int nb = (N + 127) / 128;
    int nsb = (N + 255) / 256;          // scan blocks (must be <= 256)

    // prep: cnt64 zero + x,prev_h -> bf16 + zsum=0
    {
        long long tot = (long long)N * 98 + 128;
        prep_k<<<(int)((tot + TPB - 1) / TPB), TPB, 0, stream>>>(x, prev_h, cnt64, zx, phb, zsum, N);
    }
    // weights + biases
    {
        const int cvtw_total = 2 * 32768 + 6 * 65536 + 768;
        cvtwb_k<<<(cvtw_total + TPB - 1) / TPB, TPB, 0, stream>>>(
            W1, W2, Wxz, Whz, Wxr, Whr, Wxh, Whh,
            bxz, bhz, bxr, bhr, bxh, bhh, Bt1, Bt2, BtZR, BtH, bZR, bH);
    }

    // degree + CSR
    deg_cnt_k<<<gE, TPB, 0, stream>>>(edst, ew, cnt64, E);
    scan1_k<<<nsb, 256, 0, stream>>>(cnt64, bsum, dinv, N);
    scan2_k<<<1, 256, 0, stream>>>(bsum, nsb);
    scan3_k<<<nsb, 256, 0, stream>>>(cnt64, bsum, rowp, cur, N);
    fill_csr_k<<<gE, TPB, 0, stream>>>(esrc, edst, ew, dinv, cur, csr, E);

    // t = agg(x)
    agg_bf_k<0><<<gAgg, TPB, 0, stream>>>(rowp, csr, zx, 128, 64, dinv,
                                          nullptr, buf1, 64, 0, N);

    // g = relu(t@W1 + b1) + prev_h
    mm_bf16_k<<<nb * 2, 512, 0, stream>>>(buf1, buf1, 128, 128, 128, Bt1, 128, N, 2,
                                          b1, phb, nullptr, g_bf, nullptr, EPI_G);
    // gw2 = g@W2
    mm_bf16_k<<<nb, 512, 0, stream>>>(g_bf, g_bf, 256, 256, 256, Bt2, 256, N, 1,
                                      nullptr, nullptr, nullptr, buf1, nullptr, EPI_P);
    // z = relu(agg(gw2) + b2)
    agg_bf_k<1><<<gAgg, TPB, 0, stream>>>(rowp, csr, buf1, 64, 0, dinv,
                                          b2, zx, 128, 0, N);

    // head
    colsum_bf_k<<<256, 256, 0, stream>>>(zx, zsum, N);
    head_k<<<1, 128, 0, stream>>>(zsum, Whead, bhead, (float*)d_out, 1.0f / (float)N);

    // Z|R fused GEMM
    mm_bf16_k<<<nb * 4, 512, 0, stream>>>(zx, phb, 256, 256, 256, BtZR, 512, N, 4,
                                          bZR, phb, nullptr, Zbf, buf1, EPI_ZR);
    // h GEMM
    mm_bf16_k<<<nb * 2, 512, 0, stream>>>(zx, buf1, 256, 256, 256, BtH, 512, N, 2,
                                          bH, phb, Zbf, hout, nullptr, EPI_H);
}